// Round 1
// 965.925 us; speedup vs baseline: 1.0243x; 1.0243x over previous
//
#include <hip/hip_runtime.h>
#include <cstdint>
#include <cstddef>

typedef unsigned short u16;
typedef __bf16 bf16x8 __attribute__((ext_vector_type(8)));
typedef float f32x4 __attribute__((ext_vector_type(4)));

typedef __attribute__((address_space(1))) const void global_cvoid;
typedef __attribute__((address_space(3))) void lds_void;

__device__ __forceinline__ void async16(void* lds, const void* g) {
  __builtin_amdgcn_global_load_lds((global_cvoid*)g, (lds_void*)lds, 16, 0, 0);
}

__device__ __forceinline__ u16 f2bf(float f) {  // RNE fp32 -> bf16 bits
  uint32_t u = __float_as_uint(f);
  return (u16)((u + 0x7fffu + ((u >> 16) & 1u)) >> 16);
}

// Pack 4 fp32 -> 12 u16 {h,l,h} stream, written as 6 dwords.
__device__ __forceinline__ void pack4_hlh(uint32_t* dst, const float* v) {
  u16 h[4], l[4];
#pragma unroll
  for (int u = 0; u < 4; ++u) {
    h[u] = f2bf(v[u]);
    float hf = __uint_as_float((uint32_t)h[u] << 16);
    l[u] = f2bf(v[u] - hf);
  }
  dst[0] = (uint32_t)h[0] | ((uint32_t)l[0] << 16);
  dst[1] = (uint32_t)h[0] | ((uint32_t)h[1] << 16);
  dst[2] = (uint32_t)l[1] | ((uint32_t)h[1] << 16);
  dst[3] = (uint32_t)h[2] | ((uint32_t)l[2] << 16);
  dst[4] = (uint32_t)h[2] | ((uint32_t)h[3] << 16);
  dst[5] = (uint32_t)l[3] | ((uint32_t)h[3] << 16);
}

// ---------------------------------------------------------------------------
// Pack W (A operand): out[d][3c+{0,1,2}] = {hi, hi, lo} of W[d][c].
// ---------------------------------------------------------------------------
__global__ __launch_bounds__(256) void pack_w(const float* __restrict__ W,
                                              u16* __restrict__ out) {
  int idx = blockIdx.x * 256 + threadIdx.x;
  int d = idx >> 10, c = idx & 1023;
  float f = W[idx];
  u16 h = f2bf(f);
  float hf = __uint_as_float((uint32_t)h << 16);
  u16 l = f2bf(f - hf);
  u16* dst = out + (size_t)d * 3072 + 3 * c;
  dst[0] = h; dst[1] = h; dst[2] = l;
}

// ---------------------------------------------------------------------------
// Pack+transpose X (B operand): out[b][n][3c+{0,1,2}] = {h,l,h} of X[b][c][n].
// ---------------------------------------------------------------------------
__global__ __launch_bounds__(256) void pack_x(const float* __restrict__ X,
                                              u16* __restrict__ out) {
  const int b = blockIdx.z, c0 = blockIdx.y * 32, n0 = blockIdx.x * 32;
  __shared__ float tile[32][33];
  const float* src = X + ((size_t)b * 1024 + c0) * 1024 + n0;
  const int tc = threadIdx.x >> 5, tn = threadIdx.x & 31;
#pragma unroll
  for (int i = 0; i < 4; ++i)
    tile[tc + i * 8][tn] = src[(size_t)(tc + i * 8) * 1024 + tn];
  __syncthreads();
  const int nl = threadIdx.x >> 3, cg = (threadIdx.x & 7) * 4;
  float v[4];
#pragma unroll
  for (int u = 0; u < 4; ++u) v[u] = tile[cg + u][nl];
  uint32_t* dst = (uint32_t*)(out + ((size_t)b * 1024 + n0 + nl) * 3072 +
                              (size_t)(c0 + cg) * 3);
  pack4_hlh(dst, v);
}

// ---------------------------------------------------------------------------
// Pack+transpose Tx: Tx[b][1024 c][77 t] -> TxPk[b][128 t][3072] {h,l,h},
// rows t>=77 zeroed. grid (4 t-tiles, 32 c-tiles, 16 b).
// ---------------------------------------------------------------------------
__global__ __launch_bounds__(256) void pack_tx(const float* __restrict__ Tx,
                                               u16* __restrict__ out) {
  const int b = blockIdx.z, c0 = blockIdx.y * 32, t0 = blockIdx.x * 32;
  __shared__ float tile[32][33];
  const float* src = Tx + ((size_t)b * 1024 + c0) * 77;
  const int tc = threadIdx.x >> 5, tn = threadIdx.x & 31;
#pragma unroll
  for (int i = 0; i < 4; ++i) {
    int t = t0 + tn;
    tile[tc + i * 8][tn] = (t < 77) ? src[(size_t)(tc + i * 8) * 77 + t] : 0.f;
  }
  __syncthreads();
  const int nl = threadIdx.x >> 3, cg = (threadIdx.x & 7) * 4;
  float v[4];
#pragma unroll
  for (int u = 0; u < 4; ++u) v[u] = tile[cg + u][nl];
  uint32_t* dst = (uint32_t*)(out + ((size_t)b * 128 + t0 + nl) * 3072 +
                              (size_t)(c0 + cg) * 3);
  pack4_hlh(dst, v);
}

// ---------------------------------------------------------------------------
// MFMA GEMM: Y[b][d][n] = sum_{k'} Apk[d][k'] * Bpk[b][n][k'] + bias[d]
// ---------------------------------------------------------------------------
__global__ __launch_bounds__(256) void gemm_mfma(
    const u16* __restrict__ Apk, const u16* __restrict__ Bpk,
    const float* __restrict__ bias, float* __restrict__ Y)
{
  const int b  = blockIdx.z;
  const int d0 = blockIdx.y * 128;
  const int n0 = blockIdx.x * 128;
  const int tid  = threadIdx.x;
  const int lane = tid & 63;
  const int w    = tid >> 6;
  const int wm   = w >> 1, wn = w & 1;

  __shared__ __align__(16) char smem[16384];
  char* smA = smem;
  char* smB = smem + 8192;

  const int lr = lane & 15;
  const int lk = (lane >> 4) * 8;

  const u16* Bb = Bpk + (size_t)b * 1024 * 3072;
  const char* gA0 = (const char*)(Apk + ((size_t)(d0 + (w * 2 + 0) * 16 + lr) * 3072 + lk));
  const char* gA1 = (const char*)(Apk + ((size_t)(d0 + (w * 2 + 1) * 16 + lr) * 3072 + lk));
  const char* gB0 = (const char*)(Bb  + ((size_t)(n0 + (w * 2 + 0) * 16 + lr) * 3072 + lk));
  const char* gB1 = (const char*)(Bb  + ((size_t)(n0 + (w * 2 + 1) * 16 + lr) * 3072 + lk));

  f32x4 acc[4][4];
#pragma unroll
  for (int i = 0; i < 4; ++i)
#pragma unroll
    for (int j = 0; j < 4; ++j) acc[i][j] = (f32x4){0.f, 0.f, 0.f, 0.f};

  for (int ks = 0; ks < 96; ++ks) {
    __syncthreads();
    async16(smA + (w * 2 + 0) * 1024, gA0);
    async16(smA + (w * 2 + 1) * 1024, gA1);
    async16(smB + (w * 2 + 0) * 1024, gB0);
    async16(smB + (w * 2 + 1) * 1024, gB1);
    gA0 += 64; gA1 += 64; gB0 += 64; gB1 += 64;
    __syncthreads();

    bf16x8 af[4], bfv[4];
#pragma unroll
    for (int i = 0; i < 4; ++i)
      af[i] = *(const bf16x8*)(smA + (wm * 4 + i) * 1024 + lane * 16);
#pragma unroll
    for (int j = 0; j < 4; ++j)
      bfv[j] = *(const bf16x8*)(smB + (wn * 4 + j) * 1024 + lane * 16);
#pragma unroll
    for (int i = 0; i < 4; ++i)
#pragma unroll
      for (int j = 0; j < 4; ++j)
        acc[i][j] = __builtin_amdgcn_mfma_f32_16x16x32_bf16(af[i], bfv[j], acc[i][j], 0, 0, 0);
  }

#pragma unroll
  for (int i = 0; i < 4; ++i) {
    const int dbase = d0 + wm * 64 + i * 16 + (lane >> 4) * 4;
    const float4 bv = *(const float4*)(bias + dbase);
#pragma unroll
    for (int j = 0; j < 4; ++j) {
      const int n = n0 + wn * 64 + j * 16 + lr;
      float* yp = Y + ((size_t)b * 1024 + dbase) * 1024 + n;
      yp[0]        = acc[i][j].x + bv.x;
      yp[1024]     = acc[i][j].y + bv.y;
      yp[2 * 1024] = acc[i][j].z + bv.z;
      yp[3 * 1024] = acc[i][j].w + bv.w;
    }
  }
}

// ---------------------------------------------------------------------------
// KV MFMA GEMM: kv[b][e][t(80pad)] = sum Wkv[e][c] Tx[b][c][t] + bkv[e]
// ---------------------------------------------------------------------------
__global__ __launch_bounds__(256) void gemm_kv_mfma(
    const u16* __restrict__ Apk, const u16* __restrict__ Bpk,
    const float* __restrict__ bias, float* __restrict__ Y)
{
  const int b  = blockIdx.y;
  const int d0 = blockIdx.x * 128;
  const int tid  = threadIdx.x;
  const int lane = tid & 63;
  const int w    = tid >> 6;
  const int wm   = w >> 1, wn = w & 1;

  __shared__ __align__(16) char smem[16384];
  char* smA = smem;
  char* smB = smem + 8192;

  const int lr = lane & 15;
  const int lk = (lane >> 4) * 8;

  const u16* Bb = Bpk + (size_t)b * 128 * 3072;
  const char* gA0 = (const char*)(Apk + ((size_t)(d0 + (w * 2 + 0) * 16 + lr) * 3072 + lk));
  const char* gA1 = (const char*)(Apk + ((size_t)(d0 + (w * 2 + 1) * 16 + lr) * 3072 + lk));
  const char* gB0 = (const char*)(Bb  + ((size_t)((w * 2 + 0) * 16 + lr) * 3072 + lk));
  const char* gB1 = (const char*)(Bb  + ((size_t)((w * 2 + 1) * 16 + lr) * 3072 + lk));

  f32x4 acc[4][4];
#pragma unroll
  for (int i = 0; i < 4; ++i)
#pragma unroll
    for (int j = 0; j < 4; ++j) acc[i][j] = (f32x4){0.f, 0.f, 0.f, 0.f};

  for (int ks = 0; ks < 96; ++ks) {
    __syncthreads();
    async16(smA + (w * 2 + 0) * 1024, gA0);
    async16(smA + (w * 2 + 1) * 1024, gA1);
    async16(smB + (w * 2 + 0) * 1024, gB0);
    async16(smB + (w * 2 + 1) * 1024, gB1);
    gA0 += 64; gA1 += 64; gB0 += 64; gB1 += 64;
    __syncthreads();

    bf16x8 af[4], bfv[4];
#pragma unroll
    for (int i = 0; i < 4; ++i)
      af[i] = *(const bf16x8*)(smA + (wm * 4 + i) * 1024 + lane * 16);
#pragma unroll
    for (int j = 0; j < 4; ++j)
      bfv[j] = *(const bf16x8*)(smB + (wn * 4 + j) * 1024 + lane * 16);
#pragma unroll
    for (int i = 0; i < 4; ++i)
#pragma unroll
      for (int j = 0; j < 4; ++j)
        acc[i][j] = __builtin_amdgcn_mfma_f32_16x16x32_bf16(af[i], bfv[j], acc[i][j], 0, 0, 0);
  }

#pragma unroll
  for (int i = 0; i < 4; ++i) {
    const int dbase = d0 + wm * 64 + i * 16 + (lane >> 4) * 4;
    const float4 bv = *(const float4*)(bias + dbase);
#pragma unroll
    for (int j = 0; j < 4; ++j) {
      const int n = wn * 64 + j * 16 + lr;
      if (n < 80) {
        float* yp = Y + ((size_t)b * 2048 + dbase) * 80 + n;
        yp[0]      = acc[i][j].x + bv.x;
        yp[80]     = acc[i][j].y + bv.y;
        yp[160]    = acc[i][j].z + bv.z;
        yp[240]    = acc[i][j].w + bv.w;
      }
    }
  }
}

// ---------------------------------------------------------------------------
// Attention v3: occupancy fix. 1 n per thread, 128-thread blocks,
// grid (8, 8, 16) = 1024 blocks -> 4 blocks/CU (LDS 40 KiB x 4 = 160 KiB),
// 8 waves/CU vs the previous 4 (grid was 256 blocks = 1 block/CU).
// Scores stay in registers (80 floats/thread, ~half the old VGPR pressure).
// kv layout [b][2048][80]; K pad cols (77..79) excluded from softmax,
// V pad multiplied by p=0. Coalesced fp32 output [b][c][n].
// ---------------------------------------------------------------------------
__global__ __launch_bounds__(128, 2) void attn_kernel3(
    const float* __restrict__ q,   // [B][1024][1024]
    const float* __restrict__ kv,  // [B][2048][80]
    float* __restrict__ o)         // [B][1024][1024]
{
  const int b   = blockIdx.z;
  const int h   = blockIdx.y;
  const int n0  = blockIdx.x * 128;
  const int tid = threadIdx.x;
  const float scale = 0.08838834764831845f;  // 128^-0.5

  __shared__ float sk[128 * 80];
  float4* sk4 = (float4*)sk;

  const float4* kvb4 = (const float4*)(kv + ((size_t)b * 2048 + h * 256) * 80);

  // stage K: 128 rows x 20 float4 = 2560 float4s, 20 per thread
#pragma unroll
  for (int i = 0; i < 20; ++i) sk4[tid + i * 128] = kvb4[tid + i * 128];
  __syncthreads();

  float s[80];
#pragma unroll
  for (int t = 0; t < 80; ++t) s[t] = 0.f;

  const float* qp = q + ((size_t)b * 1024 + h * 128) * 1024 + n0 + tid;
#pragma unroll 8
  for (int d = 0; d < 128; ++d) {
    float qa = qp[(size_t)d * 1024];
#pragma unroll
    for (int tc = 0; tc < 20; ++tc) {
      float4 k4 = sk4[d * 20 + tc];
      s[tc * 4 + 0] += qa * k4.x;
      s[tc * 4 + 1] += qa * k4.y;
      s[tc * 4 + 2] += qa * k4.z;
      s[tc * 4 + 3] += qa * k4.w;
    }
  }

  float m0 = -3.0e38f;
#pragma unroll
  for (int t = 0; t < 77; ++t) m0 = fmaxf(m0, s[t]);
  float sum0 = 0.f;
#pragma unroll
  for (int t = 0; t < 77; ++t) {
    s[t] = __expf((s[t] - m0) * scale); sum0 += s[t];
  }
  const float i0 = 1.f / sum0;
#pragma unroll
  for (int t = 0; t < 77; ++t) s[t] *= i0;
  s[77] = s[78] = s[79] = 0.f;

  __syncthreads();
  // stage V
  const float4* vvb4 = kvb4 + 2560;
#pragma unroll
  for (int i = 0; i < 20; ++i) sk4[tid + i * 128] = vvb4[tid + i * 128];
  __syncthreads();

  float* op = o + ((size_t)b * 1024 + h * 128) * 1024 + n0 + tid;
#pragma unroll
  for (int dblk = 0; dblk < 16; ++dblk) {
    float a0[8];
#pragma unroll
    for (int dd = 0; dd < 8; ++dd) a0[dd] = 0.f;
#pragma unroll
    for (int dd = 0; dd < 8; ++dd) {
      const int d = dblk * 8 + dd;
#pragma unroll
      for (int tc = 0; tc < 20; ++tc) {
        float4 v4 = sk4[d * 20 + tc];
        a0[dd] += v4.x * s[tc * 4 + 0] + v4.y * s[tc * 4 + 1] +
                  v4.z * s[tc * 4 + 2] + v4.w * s[tc * 4 + 3];
      }
    }
#pragma unroll
    for (int dd = 0; dd < 8; ++dd)
      op[(size_t)(dblk * 8 + dd) * 1024] = a0[dd];
  }
}

// ---------------------------------------------------------------------------
extern "C" void kernel_launch(void* const* d_in, const int* in_sizes, int n_in,
                              void* d_out, int out_size, void* d_ws, size_t ws_size,
                              hipStream_t stream) {
  const float* Vx  = (const float*)d_in[0];
  const float* Tx  = (const float*)d_in[1];
  const float* Wq  = (const float*)d_in[2];
  const float* bq  = (const float*)d_in[3];
  const float* Wkv = (const float*)d_in[4];
  const float* bkv = (const float*)d_in[5];
  const float* Wp  = (const float*)d_in[6];
  const float* bp  = (const float*)d_in[7];
  float* out = (float*)d_out;

  char* ws = (char*)d_ws;
  const size_t MiB = (size_t)1 << 20;
  // Lifetime-aliased layout (total 241 MiB):
  //   q        [0,   64)  MiB  — live gemm#1 .. attn
  //   attn_out [64, 128)  MiB  — written by attn; before that, the region
  //     holds WqPk(64-70), WkvPk(70-82), TxPk(82-94), all dead before attn.
  //   Xpk      [128, 224) MiB  — Vx-pack (dead after gemm#1), then attn-out pack
  //   kvbuf    [224, 235) MiB  — live kv_mfma .. attn
  //   WpPk     [235, 241) MiB  — live until final gemm
  float* q        = (float*)(ws + 0);
  float* attn_out = (float*)(ws + 64 * MiB);
  u16*   WqPk     = (u16*)(ws + 64 * MiB);
  u16*   WkvPk    = (u16*)(ws + 70 * MiB);
  u16*   TxPk     = (u16*)(ws + 82 * MiB);
  u16*   Xpk      = (u16*)(ws + 128 * MiB);
  float* kvbuf    = (float*)(ws + 224 * MiB);
  u16*   WpPk     = (u16*)(ws + 235 * MiB);

  pack_w<<<4096, 256, 0, stream>>>(Wq, WqPk);
  pack_w<<<4096, 256, 0, stream>>>(Wp, WpPk);
  pack_w<<<8192, 256, 0, stream>>>(Wkv, WkvPk);
  pack_x<<<dim3(32, 32, 16), 256, 0, stream>>>(Vx, Xpk);
  pack_tx<<<dim3(4, 32, 16), 256, 0, stream>>>(Tx, TxPk);
  gemm_mfma<<<dim3(8, 8, 16), 256, 0, stream>>>(WqPk, Xpk, bq, q);
  gemm_kv_mfma<<<dim3(16, 16), 256, 0, stream>>>(WkvPk, TxPk, bkv, kvbuf);
  attn_kernel3<<<dim3(8, 8, 16), 128, 0, stream>>>(q, kvbuf, attn_out);
  pack_x<<<dim3(32, 32, 16), 256, 0, stream>>>(attn_out, Xpk);
  gemm_mfma<<<dim3(8, 8, 16), 256, 0, stream>>>(WpPk, Xpk, bp, out);
}

// Round 3
// 814.109 us; speedup vs baseline: 1.2153x; 1.1865x over previous
//
#include <hip/hip_runtime.h>
#include <cstdint>
#include <cstddef>

typedef unsigned short u16;
typedef __bf16 bf16x8 __attribute__((ext_vector_type(8)));
typedef float f32x4 __attribute__((ext_vector_type(4)));

typedef __attribute__((address_space(1))) const void global_cvoid;
typedef __attribute__((address_space(3))) void lds_void;

__device__ __forceinline__ void async16(void* lds, const void* g) {
  __builtin_amdgcn_global_load_lds((global_cvoid*)g, (lds_void*)lds, 16, 0, 0);
}

__device__ __forceinline__ u16 f2bf(float f) {  // RNE fp32 -> bf16 bits
  uint32_t u = __float_as_uint(f);
  return (u16)((u + 0x7fffu + ((u >> 16) & 1u)) >> 16);
}

// Pack 4 fp32 -> 12 u16 {h,l,h} stream (B-side pattern), written as 6 dwords.
__device__ __forceinline__ void pack4_hlh(uint32_t* dst, const float* v) {
  u16 h[4], l[4];
#pragma unroll
  for (int u = 0; u < 4; ++u) {
    h[u] = f2bf(v[u]);
    float hf = __uint_as_float((uint32_t)h[u] << 16);
    l[u] = f2bf(v[u] - hf);
  }
  dst[0] = (uint32_t)h[0] | ((uint32_t)l[0] << 16);
  dst[1] = (uint32_t)h[0] | ((uint32_t)h[1] << 16);
  dst[2] = (uint32_t)l[1] | ((uint32_t)h[1] << 16);
  dst[3] = (uint32_t)h[2] | ((uint32_t)l[2] << 16);
  dst[4] = (uint32_t)h[2] | ((uint32_t)h[3] << 16);
  dst[5] = (uint32_t)l[3] | ((uint32_t)h[3] << 16);
}

// Pack 4 fp32 -> 12 u16 {h,h,l} stream (A-side pattern), 6 dwords.
// Complementary to {h,l,h}: products give h*h + h*l + l*h per value.
__device__ __forceinline__ void pack4_hhl(uint32_t* dst, const float* v) {
  u16 h[4], l[4];
#pragma unroll
  for (int u = 0; u < 4; ++u) {
    h[u] = f2bf(v[u]);
    float hf = __uint_as_float((uint32_t)h[u] << 16);
    l[u] = f2bf(v[u] - hf);
  }
  dst[0] = (uint32_t)h[0] | ((uint32_t)h[0] << 16);
  dst[1] = (uint32_t)l[0] | ((uint32_t)h[1] << 16);
  dst[2] = (uint32_t)h[1] | ((uint32_t)l[1] << 16);
  dst[3] = (uint32_t)h[2] | ((uint32_t)h[2] << 16);
  dst[4] = (uint32_t)l[2] | ((uint32_t)h[3] << 16);
  dst[5] = (uint32_t)h[3] | ((uint32_t)l[3] << 16);
}

// ---------------------------------------------------------------------------
// Pack W (A operand): out[d][3c+{0,1,2}] = {hi, hi, lo} of W[d][c].
// ---------------------------------------------------------------------------
__global__ __launch_bounds__(256) void pack_w(const float* __restrict__ W,
                                              u16* __restrict__ out) {
  int idx = blockIdx.x * 256 + threadIdx.x;
  int d = idx >> 10, c = idx & 1023;
  float f = W[idx];
  u16 h = f2bf(f);
  float hf = __uint_as_float((uint32_t)h << 16);
  u16 l = f2bf(f - hf);
  u16* dst = out + (size_t)d * 3072 + 3 * c;
  dst[0] = h; dst[1] = h; dst[2] = l;
}

// ---------------------------------------------------------------------------
// Pack+transpose X (B operand): out[b][n][3c+{0,1,2}] = {h,l,h} of X[b][c][n].
// ---------------------------------------------------------------------------
__global__ __launch_bounds__(256) void pack_x(const float* __restrict__ X,
                                              u16* __restrict__ out) {
  const int b = blockIdx.z, c0 = blockIdx.y * 32, n0 = blockIdx.x * 32;
  __shared__ float tile[32][33];
  const float* src = X + ((size_t)b * 1024 + c0) * 1024 + n0;
  const int tc = threadIdx.x >> 5, tn = threadIdx.x & 31;
#pragma unroll
  for (int i = 0; i < 4; ++i)
    tile[tc + i * 8][tn] = src[(size_t)(tc + i * 8) * 1024 + tn];
  __syncthreads();
  const int nl = threadIdx.x >> 3, cg = (threadIdx.x & 7) * 4;
  float v[4];
#pragma unroll
  for (int u = 0; u < 4; ++u) v[u] = tile[cg + u][nl];
  uint32_t* dst = (uint32_t*)(out + ((size_t)b * 1024 + n0 + nl) * 3072 +
                              (size_t)(c0 + cg) * 3);
  pack4_hlh(dst, v);
}

// ---------------------------------------------------------------------------
// Pack+transpose Tx: Tx[b][1024 c][77 t] -> TxPk[b][128 t][3072] {h,l,h},
// rows t>=77 zeroed. grid (4 t-tiles, 32 c-tiles, 16 b).
// ---------------------------------------------------------------------------
__global__ __launch_bounds__(256) void pack_tx(const float* __restrict__ Tx,
                                               u16* __restrict__ out) {
  const int b = blockIdx.z, c0 = blockIdx.y * 32, t0 = blockIdx.x * 32;
  __shared__ float tile[32][33];
  const float* src = Tx + ((size_t)b * 1024 + c0) * 77;
  const int tc = threadIdx.x >> 5, tn = threadIdx.x & 31;
#pragma unroll
  for (int i = 0; i < 4; ++i) {
    int t = t0 + tn;
    tile[tc + i * 8][tn] = (t < 77) ? src[(size_t)(tc + i * 8) * 77 + t] : 0.f;
  }
  __syncthreads();
  const int nl = threadIdx.x >> 3, cg = (threadIdx.x & 7) * 4;
  float v[4];
#pragma unroll
  for (int u = 0; u < 4; ++u) v[u] = tile[cg + u][nl];
  uint32_t* dst = (uint32_t*)(out + ((size_t)b * 128 + t0 + nl) * 3072 +
                              (size_t)(c0 + cg) * 3);
  pack4_hlh(dst, v);
}

// ---------------------------------------------------------------------------
// K repack for attention: kvbuf K rows [b][h*256+d][80 t] (fp32) ->
// KTpk[(b*8+h)][t][384] = {h,h,l} over d (transposed, d-contiguous).
// grid (8 h, 16 b), 256 threads.
// ---------------------------------------------------------------------------
__global__ __launch_bounds__(256) void pack_kt(const float* __restrict__ kv,
                                               u16* __restrict__ out) {
  const int h = blockIdx.x, b = blockIdx.y;
  __shared__ float sk[128][81];
  const float* src = kv + ((size_t)b * 2048 + h * 256) * 80;
#pragma unroll
  for (int it = 0; it < 40; ++it) {
    int idx = it * 256 + threadIdx.x;  // 0..10239 over [d][t]
    sk[idx / 80][idx % 80] = src[idx];
  }
  __syncthreads();
#pragma unroll
  for (int it = 0; it < 10; ++it) {
    int idx = it * 256 + threadIdx.x;  // 0..2559 over (t, d-group)
    int t = idx >> 5, dg = (idx & 31) * 4;
    float v[4];
#pragma unroll
    for (int u = 0; u < 4; ++u) v[u] = sk[dg + u][t];
    uint32_t* dst = (uint32_t*)(out + ((size_t)(b * 8 + h) * 80 + t) * 384 +
                                (size_t)3 * dg);
    pack4_hhl(dst, v);
  }
}

// ---------------------------------------------------------------------------
// V repack for attention: kvbuf V rows [b][h*256+128+d][80 t] (fp32) ->
// Vpk[(b*8+h)][d][256] = {h,l,h} over t (k' = 3*80 = 240, cols 240..256 = 0).
// grid (8 h, 16 b), 256 threads.
// ---------------------------------------------------------------------------
__global__ __launch_bounds__(256) void pack_v(const float* __restrict__ kv,
                                              u16* __restrict__ out) {
  const int h = blockIdx.x, b = blockIdx.y;
  const float* src = kv + ((size_t)b * 2048 + h * 256 + 128) * 80;
  u16* ob = out + (size_t)(b * 8 + h) * 128 * 256;
#pragma unroll
  for (int it = 0; it < 10; ++it) {
    int idx = it * 256 + threadIdx.x;  // 0..2559 over (d, t-group)
    int d = idx / 20, tg = idx % 20;
    float4 v4 = *(const float4*)(src + (size_t)d * 80 + tg * 4);
    float v[4] = {v4.x, v4.y, v4.z, v4.w};
    uint32_t* dst = (uint32_t*)(ob + (size_t)d * 256 + 12 * tg);
    pack4_hlh(dst, v);
  }
  // zero pad cols [240,256): 128 rows x 16 u16; 256 threads -> 1 store each
  {
    int row = threadIdx.x >> 1, part = threadIdx.x & 1;
    *(uint4*)(ob + (size_t)row * 256 + 240 + part * 8) = make_uint4(0, 0, 0, 0);
  }
}

// ---------------------------------------------------------------------------
// MFMA GEMM: Y[b][d][n] = sum_{k'} Apk[d][k'] * Bpk[b][n][k'] + bias[d]
// ---------------------------------------------------------------------------
__global__ __launch_bounds__(256) void gemm_mfma(
    const u16* __restrict__ Apk, const u16* __restrict__ Bpk,
    const float* __restrict__ bias, float* __restrict__ Y)
{
  const int b  = blockIdx.z;
  const int d0 = blockIdx.y * 128;
  const int n0 = blockIdx.x * 128;
  const int tid  = threadIdx.x;
  const int lane = tid & 63;
  const int w    = tid >> 6;
  const int wm   = w >> 1, wn = w & 1;

  __shared__ __align__(16) char smem[16384];
  char* smA = smem;
  char* smB = smem + 8192;

  const int lr = lane & 15;
  const int lk = (lane >> 4) * 8;

  const u16* Bb = Bpk + (size_t)b * 1024 * 3072;
  const char* gA0 = (const char*)(Apk + ((size_t)(d0 + (w * 2 + 0) * 16 + lr) * 3072 + lk));
  const char* gA1 = (const char*)(Apk + ((size_t)(d0 + (w * 2 + 1) * 16 + lr) * 3072 + lk));
  const char* gB0 = (const char*)(Bb  + ((size_t)(n0 + (w * 2 + 0) * 16 + lr) * 3072 + lk));
  const char* gB1 = (const char*)(Bb  + ((size_t)(n0 + (w * 2 + 1) * 16 + lr) * 3072 + lk));

  f32x4 acc[4][4];
#pragma unroll
  for (int i = 0; i < 4; ++i)
#pragma unroll
    for (int j = 0; j < 4; ++j) acc[i][j] = (f32x4){0.f, 0.f, 0.f, 0.f};

  for (int ks = 0; ks < 96; ++ks) {
    __syncthreads();
    async16(smA + (w * 2 + 0) * 1024, gA0);
    async16(smA + (w * 2 + 1) * 1024, gA1);
    async16(smB + (w * 2 + 0) * 1024, gB0);
    async16(smB + (w * 2 + 1) * 1024, gB1);
    gA0 += 64; gA1 += 64; gB0 += 64; gB1 += 64;
    __syncthreads();

    bf16x8 af[4], bfv[4];
#pragma unroll
    for (int i = 0; i < 4; ++i)
      af[i] = *(const bf16x8*)(smA + (wm * 4 + i) * 1024 + lane * 16);
#pragma unroll
    for (int j = 0; j < 4; ++j)
      bfv[j] = *(const bf16x8*)(smB + (wn * 4 + j) * 1024 + lane * 16);
#pragma unroll
    for (int i = 0; i < 4; ++i)
#pragma unroll
      for (int j = 0; j < 4; ++j)
        acc[i][j] = __builtin_amdgcn_mfma_f32_16x16x32_bf16(af[i], bfv[j], acc[i][j], 0, 0, 0);
  }

#pragma unroll
  for (int i = 0; i < 4; ++i) {
    const int dbase = d0 + wm * 64 + i * 16 + (lane >> 4) * 4;
    const float4 bv = *(const float4*)(bias + dbase);
#pragma unroll
    for (int j = 0; j < 4; ++j) {
      const int n = n0 + wn * 64 + j * 16 + lr;
      float* yp = Y + ((size_t)b * 1024 + dbase) * 1024 + n;
      yp[0]        = acc[i][j].x + bv.x;
      yp[1024]     = acc[i][j].y + bv.y;
      yp[2 * 1024] = acc[i][j].z + bv.z;
      yp[3 * 1024] = acc[i][j].w + bv.w;
    }
  }
}

// ---------------------------------------------------------------------------
// KV MFMA GEMM: kv[b][e][t(80pad)] = sum Wkv[e][c] Tx[b][c][t] + bkv[e]
// ---------------------------------------------------------------------------
__global__ __launch_bounds__(256) void gemm_kv_mfma(
    const u16* __restrict__ Apk, const u16* __restrict__ Bpk,
    const float* __restrict__ bias, float* __restrict__ Y)
{
  const int b  = blockIdx.y;
  const int d0 = blockIdx.x * 128;
  const int tid  = threadIdx.x;
  const int lane = tid & 63;
  const int w    = tid >> 6;
  const int wm   = w >> 1, wn = w & 1;

  __shared__ __align__(16) char smem[16384];
  char* smA = smem;
  char* smB = smem + 8192;

  const int lr = lane & 15;
  const int lk = (lane >> 4) * 8;

  const u16* Bb = Bpk + (size_t)b * 128 * 3072;
  const char* gA0 = (const char*)(Apk + ((size_t)(d0 + (w * 2 + 0) * 16 + lr) * 3072 + lk));
  const char* gA1 = (const char*)(Apk + ((size_t)(d0 + (w * 2 + 1) * 16 + lr) * 3072 + lk));
  const char* gB0 = (const char*)(Bb  + ((size_t)((w * 2 + 0) * 16 + lr) * 3072 + lk));
  const char* gB1 = (const char*)(Bb  + ((size_t)((w * 2 + 1) * 16 + lr) * 3072 + lk));

  f32x4 acc[4][4];
#pragma unroll
  for (int i = 0; i < 4; ++i)
#pragma unroll
    for (int j = 0; j < 4; ++j) acc[i][j] = (f32x4){0.f, 0.f, 0.f, 0.f};

  for (int ks = 0; ks < 96; ++ks) {
    __syncthreads();
    async16(smA + (w * 2 + 0) * 1024, gA0);
    async16(smA + (w * 2 + 1) * 1024, gA1);
    async16(smB + (w * 2 + 0) * 1024, gB0);
    async16(smB + (w * 2 + 1) * 1024, gB1);
    gA0 += 64; gA1 += 64; gB0 += 64; gB1 += 64;
    __syncthreads();

    bf16x8 af[4], bfv[4];
#pragma unroll
    for (int i = 0; i < 4; ++i)
      af[i] = *(const bf16x8*)(smA + (wm * 4 + i) * 1024 + lane * 16);
#pragma unroll
    for (int j = 0; j < 4; ++j)
      bfv[j] = *(const bf16x8*)(smB + (wn * 4 + j) * 1024 + lane * 16);
#pragma unroll
    for (int i = 0; i < 4; ++i)
#pragma unroll
      for (int j = 0; j < 4; ++j)
        acc[i][j] = __builtin_amdgcn_mfma_f32_16x16x32_bf16(af[i], bfv[j], acc[i][j], 0, 0, 0);
  }

#pragma unroll
  for (int i = 0; i < 4; ++i) {
    const int dbase = d0 + wm * 64 + i * 16 + (lane >> 4) * 4;
    const float4 bv = *(const float4*)(bias + dbase);
#pragma unroll
    for (int j = 0; j < 4; ++j) {
      const int n = wn * 64 + j * 16 + lr;
      if (n < 80) {
        float* yp = Y + ((size_t)b * 2048 + dbase) * 80 + n;
        yp[0]      = acc[i][j].x + bv.x;
        yp[80]     = acc[i][j].y + bv.y;
        yp[160]    = acc[i][j].z + bv.z;
        yp[240]    = acc[i][j].w + bv.w;
      }
    }
  }
}

// ---------------------------------------------------------------------------
// MFMA attention. Per block: one (b,h), 128 n-rows; 4 waves x 32 rows.
// QK^T: S[n][t] = sum_d q[n][d] K[t][d], split-bf16 (k'=384, 12 MFMA steps),
// operands read directly from global (KT is 60KB/head -> L2-resident).
// Softmax in registers (16-lane shfl reduce per row group, mask t>=77).
// P written {h,h,l} to WAVE-PRIVATE LDS (no barriers in whole kernel),
// PV: out[n][d] = sum_t P[n][t] V[t][d], k'=240 pad 256 (8 MFMA steps).
// Fragment conventions identical to gemm_mfma (A/B: row=lane&15,
// kchunk=(lane>>4)*8; C/D: col=lane&15, row=(lane>>4)*4+comp).
// LDS 64 KiB -> 2 blocks/CU (8 waves/CU). grid (8 ntile, 8 h, 16 b).
// ---------------------------------------------------------------------------
__global__ __launch_bounds__(256, 2) void attn_mfma(
    const u16* __restrict__ qpk,   // [B][1024 n][3072] {h,l,h}
    const u16* __restrict__ ktpk,  // [B*8][80 t][384]  {h,h,l}
    const u16* __restrict__ vpk,   // [B*8][128 d][256] {h,l,h}, 240..256 = 0
    float* __restrict__ o)         // [B][1024 c][1024 n]
{
  const int b  = blockIdx.z;
  const int h  = blockIdx.y;
  const int n0 = blockIdx.x * 128;
  const int tid  = threadIdx.x;
  const int w    = tid >> 6;
  const int lane = tid & 63;
  const int lr = lane & 15;      // frag row / output col
  const int lc = lane >> 4;      // frag k-chunk / output row group
  const float scale = 0.08838834764831845f;  // 128^-0.5

  __shared__ u16 Plds[4][32 * 256];   // 64 KiB total, wave-private slices
  u16* Pw = &Plds[w][0];

  // zero P pad cols [240,256) for this wave's 32 rows (1 x 16B store/lane)
  {
    int row = lane & 31, part = lane >> 5;
    *(uint4*)&Pw[row * 256 + 240 + part * 8] = make_uint4(0, 0, 0, 0);
  }

  // ---------------- QK^T ----------------
  const u16* qb = qpk + ((size_t)b * 1024 + n0 + w * 32 + lr) * 3072 +
                  384 * h + lc * 8;
  const u16* kb = ktpk + (size_t)(b * 8 + h) * 80 * 384 + (size_t)lr * 384 + lc * 8;

  f32x4 accs[2][5];
#pragma unroll
  for (int ni = 0; ni < 2; ++ni)
#pragma unroll
    for (int tt = 0; tt < 5; ++tt) accs[ni][tt] = (f32x4){0.f, 0.f, 0.f, 0.f};

  for (int ks = 0; ks < 12; ++ks) {
    bf16x8 qa[2], kt[5];
    qa[0] = *(const bf16x8*)(qb + ks * 32);
    qa[1] = *(const bf16x8*)(qb + 16 * 3072 + ks * 32);
#pragma unroll
    for (int tt = 0; tt < 5; ++tt)
      kt[tt] = *(const bf16x8*)(kb + (size_t)tt * 16 * 384 + ks * 32);
#pragma unroll
    for (int ni = 0; ni < 2; ++ni)
#pragma unroll
      for (int tt = 0; tt < 5; ++tt)
        accs[ni][tt] = __builtin_amdgcn_mfma_f32_16x16x32_bf16(qa[ni], kt[tt], accs[ni][tt], 0, 0, 0);
  }

  // mask t >= 77 (t = tt*16 + lr; only tt==4, lr>=13 invalid)
  if (lr >= 13) {
    accs[0][4] = (f32x4){-3.0e38f, -3.0e38f, -3.0e38f, -3.0e38f};
    accs[1][4] = (f32x4){-3.0e38f, -3.0e38f, -3.0e38f, -3.0e38f};
  }

  // ---------------- softmax + P pack to LDS ----------------
#pragma unroll
  for (int ni = 0; ni < 2; ++ni) {
    f32x4 mx = accs[ni][0];
#pragma unroll
    for (int tt = 1; tt < 5; ++tt) {
      mx.x = fmaxf(mx.x, accs[ni][tt].x);
      mx.y = fmaxf(mx.y, accs[ni][tt].y);
      mx.z = fmaxf(mx.z, accs[ni][tt].z);
      mx.w = fmaxf(mx.w, accs[ni][tt].w);
    }
#pragma unroll
    for (int mk = 1; mk <= 8; mk <<= 1) {
      mx.x = fmaxf(mx.x, __shfl_xor(mx.x, mk));
      mx.y = fmaxf(mx.y, __shfl_xor(mx.y, mk));
      mx.z = fmaxf(mx.z, __shfl_xor(mx.z, mk));
      mx.w = fmaxf(mx.w, __shfl_xor(mx.w, mk));
    }
    f32x4 sm = (f32x4){0.f, 0.f, 0.f, 0.f};
#pragma unroll
    for (int tt = 0; tt < 5; ++tt) {
      f32x4 e;
      e.x = __expf((accs[ni][tt].x - mx.x) * scale);
      e.y = __expf((accs[ni][tt].y - mx.y) * scale);
      e.z = __expf((accs[ni][tt].z - mx.z) * scale);
      e.w = __expf((accs[ni][tt].w - mx.w) * scale);
      accs[ni][tt] = e;
      sm += e;
    }
#pragma unroll
    for (int mk = 1; mk <= 8; mk <<= 1) {
      sm.x += __shfl_xor(sm.x, mk);
      sm.y += __shfl_xor(sm.y, mk);
      sm.z += __shfl_xor(sm.z, mk);
      sm.w += __shfl_xor(sm.w, mk);
    }
    f32x4 inv = (f32x4){1.f / sm.x, 1.f / sm.y, 1.f / sm.z, 1.f / sm.w};
    // write P {h,h,l} at [row][3t..3t+2]; row = ni*16 + lc*4 + comp, t = tt*16+lr
#pragma unroll
    for (int tt = 0; tt < 5; ++tt) {
#pragma unroll
      for (int c = 0; c < 4; ++c) {
        float pv = accs[ni][tt][c] * inv[c];
        int row = ni * 16 + lc * 4 + c;
        int t = tt * 16 + lr;
        u16 hh = f2bf(pv);
        float hf = __uint_as_float((uint32_t)hh << 16);
        u16 ll = f2bf(pv - hf);
        u16* pp = &Pw[row * 256 + 3 * t];
        pp[0] = hh; pp[1] = hh; pp[2] = ll;
      }
    }
  }

  // ---------------- PV ----------------
  f32x4 acco[2][8];
#pragma unroll
  for (int ni = 0; ni < 2; ++ni)
#pragma unroll
    for (int dj = 0; dj < 8; ++dj) acco[ni][dj] = (f32x4){0.f, 0.f, 0.f, 0.f};

  const u16* vb = vpk + (size_t)(b * 8 + h) * 128 * 256 + (size_t)lr * 256 + lc * 8;
  const u16* pb = &Pw[lr * 256 + lc * 8];

  for (int ks = 0; ks < 8; ++ks) {
    bf16x8 pa[2], vv[8];
    pa[0] = *(const bf16x8*)(pb + ks * 32);
    pa[1] = *(const bf16x8*)(pb + 16 * 256 + ks * 32);
#pragma unroll
    for (int dj = 0; dj < 8; ++dj)
      vv[dj] = *(const bf16x8*)(vb + (size_t)dj * 16 * 256 + ks * 32);
#pragma unroll
    for (int ni = 0; ni < 2; ++ni)
#pragma unroll
      for (int dj = 0; dj < 8; ++dj)
        acco[ni][dj] = __builtin_amdgcn_mfma_f32_16x16x32_bf16(pa[ni], vv[dj], acco[ni][dj], 0, 0, 0);
  }

  // ---------------- epilogue: out[b][h*128+d][n], float4 over 4 n ----------
#pragma unroll
  for (int ni = 0; ni < 2; ++ni) {
#pragma unroll
    for (int dj = 0; dj < 8; ++dj) {
      int d = h * 128 + dj * 16 + lr;
      int n = n0 + w * 32 + ni * 16 + lc * 4;
      *(f32x4*)(o + ((size_t)b * 1024 + d) * 1024 + n) = acco[ni][dj];
    }
  }
}

// ---------------------------------------------------------------------------
extern "C" void kernel_launch(void* const* d_in, const int* in_sizes, int n_in,
                              void* d_out, int out_size, void* d_ws, size_t ws_size,
                              hipStream_t stream) {
  const float* Vx  = (const float*)d_in[0];
  const float* Tx  = (const float*)d_in[1];
  const float* Wq  = (const float*)d_in[2];
  const float* bq  = (const float*)d_in[3];
  const float* Wkv = (const float*)d_in[4];
  const float* bkv = (const float*)d_in[5];
  const float* Wp  = (const float*)d_in[6];
  const float* bp  = (const float*)d_in[7];
  float* out = (float*)d_out;

  char* ws = (char*)d_ws;
  const size_t MiB = (size_t)1 << 20;
  // Lifetime-aliased layout (total 223 MiB). Step order:
  //  1 packs (W/Vx/Tx)  2 gemm q  3 gemm kv  4 pack_kt/pack_v
  //  5 pack_x(q->qpk)   6 attn    7 pack_x(attn_out->Xpk)  8 gemm out
  //   [0,  64): q (steps 2-5), then attn_out (6-7)
  //   [64,160): Xpk#1 Vx-pack (1-2), qpk (5-6), Xpk#2 attn-pack (7-8)
  //   [160,166) WqPk (1-2)   [166,178) WkvPk (1-3)  [178,190) TxPk (1-3)
  //   [190,196) WpPk (1-8)   [196,207) kvbuf (3-4)
  //   [207,215) KTpk (4-6)   [215,223) Vpk (4-6)
  float* q        = (float*)(ws + 0);
  float* attn_out = (float*)(ws + 0);
  u16*   Xpk      = (u16*)(ws + 64 * MiB);
  u16*   qpk      = (u16*)(ws + 64 * MiB);
  u16*   WqPk     = (u16*)(ws + 160 * MiB);
  u16*   WkvPk    = (u16*)(ws + 166 * MiB);
  u16*   TxPk     = (u16*)(ws + 178 * MiB);
  u16*   WpPk     = (u16*)(ws + 190 * MiB);
  float* kvbuf    = (float*)(ws + 196 * MiB);
  u16*   KTpk     = (u16*)(ws + 207 * MiB);
  u16*   Vpk      = (u16*)(ws + 215 * MiB);

  pack_w<<<4096, 256, 0, stream>>>(Wq, WqPk);
  pack_w<<<4096, 256, 0, stream>>>(Wp, WpPk);
  pack_w<<<8192, 256, 0, stream>>>(Wkv, WkvPk);
  pack_x<<<dim3(32, 32, 16), 256, 0, stream>>>(Vx, Xpk);
  pack_tx<<<dim3(4, 32, 16), 256, 0, stream>>>(Tx, TxPk);
  gemm_mfma<<<dim3(8, 8, 16), 256, 0, stream>>>(WqPk, Xpk, bq, q);
  gemm_kv_mfma<<<dim3(16, 16), 256, 0, stream>>>(WkvPk, TxPk, bkv, kvbuf);
  pack_kt<<<dim3(8, 16), 256, 0, stream>>>(kvbuf, KTpk);
  pack_v<<<dim3(8, 16), 256, 0, stream>>>(kvbuf, Vpk);
  pack_x<<<dim3(32, 32, 16), 256, 0, stream>>>(q, qpk);
  attn_mfma<<<dim3(8, 8, 16), 256, 0, stream>>>(qpk, KTpk, Vpk, attn_out);
  pack_x<<<dim3(32, 32, 16), 256, 0, stream>>>(attn_out, Xpk);
  gemm_mfma<<<dim3(8, 8, 16), 256, 0, stream>>>(WpPk, Xpk, bp, out);
}

// Round 4
// 752.368 us; speedup vs baseline: 1.3150x; 1.0821x over previous
//
#include <hip/hip_runtime.h>
#include <cstdint>
#include <cstddef>

typedef unsigned short u16;
typedef __bf16 bf16x8 __attribute__((ext_vector_type(8)));
typedef float f32x4 __attribute__((ext_vector_type(4)));

typedef __attribute__((address_space(1))) const void global_cvoid;
typedef __attribute__((address_space(3))) void lds_void;

__device__ __forceinline__ void async16(void* lds, const void* g) {
  __builtin_amdgcn_global_load_lds((global_cvoid*)g, (lds_void*)lds, 16, 0, 0);
}

__device__ __forceinline__ u16 f2bf(float f) {  // RNE fp32 -> bf16 bits
  uint32_t u = __float_as_uint(f);
  return (u16)((u + 0x7fffu + ((u >> 16) & 1u)) >> 16);
}

// Pack 4 fp32 -> 12 u16 {h,l,h} stream (B-side pattern), written as 6 dwords.
__device__ __forceinline__ void pack4_hlh(uint32_t* dst, const float* v) {
  u16 h[4], l[4];
#pragma unroll
  for (int u = 0; u < 4; ++u) {
    h[u] = f2bf(v[u]);
    float hf = __uint_as_float((uint32_t)h[u] << 16);
    l[u] = f2bf(v[u] - hf);
  }
  dst[0] = (uint32_t)h[0] | ((uint32_t)l[0] << 16);
  dst[1] = (uint32_t)h[0] | ((uint32_t)h[1] << 16);
  dst[2] = (uint32_t)l[1] | ((uint32_t)h[1] << 16);
  dst[3] = (uint32_t)h[2] | ((uint32_t)l[2] << 16);
  dst[4] = (uint32_t)h[2] | ((uint32_t)h[3] << 16);
  dst[5] = (uint32_t)l[3] | ((uint32_t)h[3] << 16);
}

// Pack 4 fp32 -> 12 u16 {h,h,l} stream (A-side pattern), 6 dwords.
// Complementary to {h,l,h}: products give h*h + h*l + l*h per value.
__device__ __forceinline__ void pack4_hhl(uint32_t* dst, const float* v) {
  u16 h[4], l[4];
#pragma unroll
  for (int u = 0; u < 4; ++u) {
    h[u] = f2bf(v[u]);
    float hf = __uint_as_float((uint32_t)h[u] << 16);
    l[u] = f2bf(v[u] - hf);
  }
  dst[0] = (uint32_t)h[0] | ((uint32_t)h[0] << 16);
  dst[1] = (uint32_t)l[0] | ((uint32_t)h[1] << 16);
  dst[2] = (uint32_t)h[1] | ((uint32_t)l[1] << 16);
  dst[3] = (uint32_t)h[2] | ((uint32_t)h[2] << 16);
  dst[4] = (uint32_t)l[2] | ((uint32_t)h[3] << 16);
  dst[5] = (uint32_t)h[3] | ((uint32_t)l[3] << 16);
}

// ---------------------------------------------------------------------------
// Pack W (A operand): out[d][3c+{0,1,2}] = {hi, hi, lo} of W[d][c].
// ---------------------------------------------------------------------------
__global__ __launch_bounds__(256) void pack_w(const float* __restrict__ W,
                                              u16* __restrict__ out) {
  int idx = blockIdx.x * 256 + threadIdx.x;
  int d = idx >> 10, c = idx & 1023;
  float f = W[idx];
  u16 h = f2bf(f);
  float hf = __uint_as_float((uint32_t)h << 16);
  u16 l = f2bf(f - hf);
  u16* dst = out + (size_t)d * 3072 + 3 * c;
  dst[0] = h; dst[1] = h; dst[2] = l;
}

// ---------------------------------------------------------------------------
// Pack+transpose X (B operand): out[b][n][3c+{0,1,2}] = {h,l,h} of X[b][c][n].
// ---------------------------------------------------------------------------
__global__ __launch_bounds__(256) void pack_x(const float* __restrict__ X,
                                              u16* __restrict__ out) {
  const int b = blockIdx.z, c0 = blockIdx.y * 32, n0 = blockIdx.x * 32;
  __shared__ float tile[32][33];
  const float* src = X + ((size_t)b * 1024 + c0) * 1024 + n0;
  const int tc = threadIdx.x >> 5, tn = threadIdx.x & 31;
#pragma unroll
  for (int i = 0; i < 4; ++i)
    tile[tc + i * 8][tn] = src[(size_t)(tc + i * 8) * 1024 + tn];
  __syncthreads();
  const int nl = threadIdx.x >> 3, cg = (threadIdx.x & 7) * 4;
  float v[4];
#pragma unroll
  for (int u = 0; u < 4; ++u) v[u] = tile[cg + u][nl];
  uint32_t* dst = (uint32_t*)(out + ((size_t)b * 1024 + n0 + nl) * 3072 +
                              (size_t)(c0 + cg) * 3);
  pack4_hlh(dst, v);
}

// ---------------------------------------------------------------------------
// Pack+transpose Tx: Tx[b][1024 c][77 t] -> TxPk[b][128 t][3072] {h,l,h},
// rows t>=77 zeroed. grid (4 t-tiles, 32 c-tiles, 16 b).
// ---------------------------------------------------------------------------
__global__ __launch_bounds__(256) void pack_tx(const float* __restrict__ Tx,
                                               u16* __restrict__ out) {
  const int b = blockIdx.z, c0 = blockIdx.y * 32, t0 = blockIdx.x * 32;
  __shared__ float tile[32][33];
  const float* src = Tx + ((size_t)b * 1024 + c0) * 77;
  const int tc = threadIdx.x >> 5, tn = threadIdx.x & 31;
#pragma unroll
  for (int i = 0; i < 4; ++i) {
    int t = t0 + tn;
    tile[tc + i * 8][tn] = (t < 77) ? src[(size_t)(tc + i * 8) * 77 + t] : 0.f;
  }
  __syncthreads();
  const int nl = threadIdx.x >> 3, cg = (threadIdx.x & 7) * 4;
  float v[4];
#pragma unroll
  for (int u = 0; u < 4; ++u) v[u] = tile[cg + u][nl];
  uint32_t* dst = (uint32_t*)(out + ((size_t)b * 128 + t0 + nl) * 3072 +
                              (size_t)(c0 + cg) * 3);
  pack4_hlh(dst, v);
}

// ---------------------------------------------------------------------------
// K repack for attention: kvbuf K rows [b][h*256+d][80 t] (fp32) ->
// KTpk[(b*8+h)][t][384] = {h,h,l} over d (transposed, d-contiguous).
// grid (8 h, 16 b), 256 threads.
// ---------------------------------------------------------------------------
__global__ __launch_bounds__(256) void pack_kt(const float* __restrict__ kv,
                                               u16* __restrict__ out) {
  const int h = blockIdx.x, b = blockIdx.y;
  __shared__ float sk[128][81];
  const float* src = kv + ((size_t)b * 2048 + h * 256) * 80;
#pragma unroll
  for (int it = 0; it < 40; ++it) {
    int idx = it * 256 + threadIdx.x;  // 0..10239 over [d][t]
    sk[idx / 80][idx % 80] = src[idx];
  }
  __syncthreads();
#pragma unroll
  for (int it = 0; it < 10; ++it) {
    int idx = it * 256 + threadIdx.x;  // 0..2559 over (t, d-group)
    int t = idx >> 5, dg = (idx & 31) * 4;
    float v[4];
#pragma unroll
    for (int u = 0; u < 4; ++u) v[u] = sk[dg + u][t];
    uint32_t* dst = (uint32_t*)(out + ((size_t)(b * 8 + h) * 80 + t) * 384 +
                                (size_t)3 * dg);
    pack4_hhl(dst, v);
  }
}

// ---------------------------------------------------------------------------
// V repack for attention: kvbuf V rows [b][h*256+128+d][80 t] (fp32) ->
// Vpk[(b*8+h)][d][256] = {h,l,h} over t (k' = 3*80 = 240, cols 240..256 = 0).
// grid (8 h, 16 b), 256 threads.
// ---------------------------------------------------------------------------
__global__ __launch_bounds__(256) void pack_v(const float* __restrict__ kv,
                                              u16* __restrict__ out) {
  const int h = blockIdx.x, b = blockIdx.y;
  const float* src = kv + ((size_t)b * 2048 + h * 256 + 128) * 80;
  u16* ob = out + (size_t)(b * 8 + h) * 128 * 256;
#pragma unroll
  for (int it = 0; it < 10; ++it) {
    int idx = it * 256 + threadIdx.x;  // 0..2559 over (d, t-group)
    int d = idx / 20, tg = idx % 20;
    float4 v4 = *(const float4*)(src + (size_t)d * 80 + tg * 4);
    float v[4] = {v4.x, v4.y, v4.z, v4.w};
    uint32_t* dst = (uint32_t*)(ob + (size_t)d * 256 + 12 * tg);
    pack4_hlh(dst, v);
  }
  // zero pad cols [240,256): 128 rows x 16 u16; 256 threads -> 1 store each
  {
    int row = threadIdx.x >> 1, part = threadIdx.x & 1;
    *(uint4*)(ob + (size_t)row * 256 + 240 + part * 8) = make_uint4(0, 0, 0, 0);
  }
}

// ---------------------------------------------------------------------------
// MFMA GEMM (2-phase double-buffered): Y[b][d][n] = A[d][k']·B[b][n][k']+bias.
// BK'=64 u16 (2 MFMA k-slices) per step -> 48 steps, ONE barrier per step.
// Next-tile global_load_lds issued BEFORE ds_read+MFMA of current tile, so
// load latency hides under compute; the single __syncthreads (vmcnt drain)
// lands after the MFMAs. LDS: 2 bufs x (A 16K + B 16K) = 64 KiB, 2 blk/CU.
// Fragment-linear LDS: frag (k2, s) at (k2*8+s)*1024, read at lane*16
// (conflict-free); global source pre-swizzled per-lane (row=lane&15,
// kchunk=(lane>>4)*8), matching gfx950 global_load_lds lane x 16B layout.
// ---------------------------------------------------------------------------
__global__ __launch_bounds__(256) void gemm_mfma(
    const u16* __restrict__ Apk, const u16* __restrict__ Bpk,
    const float* __restrict__ bias, float* __restrict__ Y)
{
  const int b  = blockIdx.z;
  const int d0 = blockIdx.y * 128;
  const int n0 = blockIdx.x * 128;
  const int tid  = threadIdx.x;
  const int lane = tid & 63;
  const int w    = tid >> 6;
  const int wm   = w >> 1, wn = w & 1;

  __shared__ __align__(16) char smem[65536];

  const int lr = lane & 15;
  const int lk = (lane >> 4) * 8;

  const u16* Bb = Bpk + (size_t)b * 1024 * 3072;
  const char* gA0 = (const char*)(Apk + ((size_t)(d0 + (w * 2 + 0) * 16 + lr) * 3072 + lk));
  const char* gA1 = (const char*)(Apk + ((size_t)(d0 + (w * 2 + 1) * 16 + lr) * 3072 + lk));
  const char* gB0 = (const char*)(Bb  + ((size_t)(n0 + (w * 2 + 0) * 16 + lr) * 3072 + lk));
  const char* gB1 = (const char*)(Bb  + ((size_t)(n0 + (w * 2 + 1) * 16 + lr) * 3072 + lk));

  // stage tile ks into buffer p: 8 frags/wave (A s=2w,2w+1 x k2=0,1; B same)
  auto stage = [&](int p, int ks) {
    char* ba = smem + p * 32768 + (w * 2) * 1024;
    char* bb = ba + 16384;
    const int kb = ks * 128;
#pragma unroll
    for (int k2 = 0; k2 < 2; ++k2) {
      async16(ba + k2 * 8192,        gA0 + kb + k2 * 64);
      async16(ba + k2 * 8192 + 1024, gA1 + kb + k2 * 64);
      async16(bb + k2 * 8192,        gB0 + kb + k2 * 64);
      async16(bb + k2 * 8192 + 1024, gB1 + kb + k2 * 64);
    }
  };

  f32x4 acc[4][4];
#pragma unroll
  for (int i = 0; i < 4; ++i)
#pragma unroll
    for (int j = 0; j < 4; ++j) acc[i][j] = (f32x4){0.f, 0.f, 0.f, 0.f};

  stage(0, 0);
  __syncthreads();

  int p = 0;
  for (int ks = 0; ks < 48; ++ks) {
    if (ks < 47) stage(p ^ 1, ks + 1);   // prefetch next tile (other buffer)
    const char* baseA = smem + p * 32768 + wm * 4096 + lane * 16;
    const char* baseB = smem + p * 32768 + 16384 + wn * 4096 + lane * 16;
#pragma unroll
    for (int k2 = 0; k2 < 2; ++k2) {
      bf16x8 af[4], bfv[4];
#pragma unroll
      for (int i = 0; i < 4; ++i) {
        af[i]  = *(const bf16x8*)(baseA + k2 * 8192 + i * 1024);
        bfv[i] = *(const bf16x8*)(baseB + k2 * 8192 + i * 1024);
      }
#pragma unroll
      for (int i = 0; i < 4; ++i)
#pragma unroll
        for (int j = 0; j < 4; ++j)
          acc[i][j] = __builtin_amdgcn_mfma_f32_16x16x32_bf16(af[i], bfv[j], acc[i][j], 0, 0, 0);
    }
    __syncthreads();   // drains prefetch (vmcnt) AFTER compute; frees buf p
    p ^= 1;
  }

#pragma unroll
  for (int i = 0; i < 4; ++i) {
    const int dbase = d0 + wm * 64 + i * 16 + (lane >> 4) * 4;
    const float4 bv = *(const float4*)(bias + dbase);
#pragma unroll
    for (int j = 0; j < 4; ++j) {
      const int n = n0 + wn * 64 + j * 16 + lr;
      float* yp = Y + ((size_t)b * 1024 + dbase) * 1024 + n;
      yp[0]        = acc[i][j].x + bv.x;
      yp[1024]     = acc[i][j].y + bv.y;
      yp[2 * 1024] = acc[i][j].z + bv.z;
      yp[3 * 1024] = acc[i][j].w + bv.w;
    }
  }
}

// ---------------------------------------------------------------------------
// KV MFMA GEMM (same 2-phase structure): kv[b][e][t(80pad)] =
// sum Wkv[e][c] Tx[b][c][t] + bkv[e]
// ---------------------------------------------------------------------------
__global__ __launch_bounds__(256) void gemm_kv_mfma(
    const u16* __restrict__ Apk, const u16* __restrict__ Bpk,
    const float* __restrict__ bias, float* __restrict__ Y)
{
  const int b  = blockIdx.y;
  const int d0 = blockIdx.x * 128;
  const int tid  = threadIdx.x;
  const int lane = tid & 63;
  const int w    = tid >> 6;
  const int wm   = w >> 1, wn = w & 1;

  __shared__ __align__(16) char smem[65536];

  const int lr = lane & 15;
  const int lk = (lane >> 4) * 8;

  const u16* Bb = Bpk + (size_t)b * 128 * 3072;
  const char* gA0 = (const char*)(Apk + ((size_t)(d0 + (w * 2 + 0) * 16 + lr) * 3072 + lk));
  const char* gA1 = (const char*)(Apk + ((size_t)(d0 + (w * 2 + 1) * 16 + lr) * 3072 + lk));
  const char* gB0 = (const char*)(Bb  + ((size_t)((w * 2 + 0) * 16 + lr) * 3072 + lk));
  const char* gB1 = (const char*)(Bb  + ((size_t)((w * 2 + 1) * 16 + lr) * 3072 + lk));

  auto stage = [&](int p, int ks) {
    char* ba = smem + p * 32768 + (w * 2) * 1024;
    char* bb = ba + 16384;
    const int kb = ks * 128;
#pragma unroll
    for (int k2 = 0; k2 < 2; ++k2) {
      async16(ba + k2 * 8192,        gA0 + kb + k2 * 64);
      async16(ba + k2 * 8192 + 1024, gA1 + kb + k2 * 64);
      async16(bb + k2 * 8192,        gB0 + kb + k2 * 64);
      async16(bb + k2 * 8192 + 1024, gB1 + kb + k2 * 64);
    }
  };

  f32x4 acc[4][4];
#pragma unroll
  for (int i = 0; i < 4; ++i)
#pragma unroll
    for (int j = 0; j < 4; ++j) acc[i][j] = (f32x4){0.f, 0.f, 0.f, 0.f};

  stage(0, 0);
  __syncthreads();

  int p = 0;
  for (int ks = 0; ks < 48; ++ks) {
    if (ks < 47) stage(p ^ 1, ks + 1);
    const char* baseA = smem + p * 32768 + wm * 4096 + lane * 16;
    const char* baseB = smem + p * 32768 + 16384 + wn * 4096 + lane * 16;
#pragma unroll
    for (int k2 = 0; k2 < 2; ++k2) {
      bf16x8 af[4], bfv[4];
#pragma unroll
      for (int i = 0; i < 4; ++i) {
        af[i]  = *(const bf16x8*)(baseA + k2 * 8192 + i * 1024);
        bfv[i] = *(const bf16x8*)(baseB + k2 * 8192 + i * 1024);
      }
#pragma unroll
      for (int i = 0; i < 4; ++i)
#pragma unroll
        for (int j = 0; j < 4; ++j)
          acc[i][j] = __builtin_amdgcn_mfma_f32_16x16x32_bf16(af[i], bfv[j], acc[i][j], 0, 0, 0);
    }
    __syncthreads();
    p ^= 1;
  }

#pragma unroll
  for (int i = 0; i < 4; ++i) {
    const int dbase = d0 + wm * 64 + i * 16 + (lane >> 4) * 4;
    const float4 bv = *(const float4*)(bias + dbase);
#pragma unroll
    for (int j = 0; j < 4; ++j) {
      const int n = wn * 64 + j * 16 + lr;
      if (n < 80) {
        float* yp = Y + ((size_t)b * 2048 + dbase) * 80 + n;
        yp[0]      = acc[i][j].x + bv.x;
        yp[80]     = acc[i][j].y + bv.y;
        yp[160]    = acc[i][j].z + bv.z;
        yp[240]    = acc[i][j].w + bv.w;
      }
    }
  }
}

// ---------------------------------------------------------------------------
// MFMA attention. Per block: one (b,h), 128 n-rows; 4 waves x 32 rows.
// QK^T: S[n][t] = sum_d q[n][d] K[t][d], split-bf16 (k'=384, 12 MFMA steps),
// operands read directly from global (KT is 60KB/head -> L2-resident).
// Softmax in registers (16-lane shfl reduce per row group, mask t>=77).
// P written {h,h,l} to WAVE-PRIVATE LDS (no barriers in whole kernel),
// PV: out[n][d] = sum_t P[n][t] V[t][d], k'=240 pad 256 (8 MFMA steps).
// Fragment conventions identical to gemm_mfma (A/B: row=lane&15,
// kchunk=(lane>>4)*8; C/D: col=lane&15, row=(lane>>4)*4+comp).
// LDS 64 KiB -> 2 blocks/CU (8 waves/CU). grid (8 ntile, 8 h, 16 b).
// ---------------------------------------------------------------------------
__global__ __launch_bounds__(256, 2) void attn_mfma(
    const u16* __restrict__ qpk,   // [B][1024 n][3072] {h,l,h}
    const u16* __restrict__ ktpk,  // [B*8][80 t][384]  {h,h,l}
    const u16* __restrict__ vpk,   // [B*8][128 d][256] {h,l,h}, 240..256 = 0
    float* __restrict__ o)         // [B][1024 c][1024 n]
{
  const int b  = blockIdx.z;
  const int h  = blockIdx.y;
  const int n0 = blockIdx.x * 128;
  const int tid  = threadIdx.x;
  const int w    = tid >> 6;
  const int lane = tid & 63;
  const int lr = lane & 15;      // frag row / output col
  const int lc = lane >> 4;      // frag k-chunk / output row group
  const float scale = 0.08838834764831845f;  // 128^-0.5

  __shared__ u16 Plds[4][32 * 256];   // 64 KiB total, wave-private slices
  u16* Pw = &Plds[w][0];

  // zero P pad cols [240,256) for this wave's 32 rows (1 x 16B store/lane)
  {
    int row = lane & 31, part = lane >> 5;
    *(uint4*)&Pw[row * 256 + 240 + part * 8] = make_uint4(0, 0, 0, 0);
  }

  // ---------------- QK^T ----------------
  const u16* qb = qpk + ((size_t)b * 1024 + n0 + w * 32 + lr) * 3072 +
                  384 * h + lc * 8;
  const u16* kb = ktpk + (size_t)(b * 8 + h) * 80 * 384 + (size_t)lr * 384 + lc * 8;

  f32x4 accs[2][5];
#pragma unroll
  for (int ni = 0; ni < 2; ++ni)
#pragma unroll
    for (int tt = 0; tt < 5; ++tt) accs[ni][tt] = (f32x4){0.f, 0.f, 0.f, 0.f};

  for (int ks = 0; ks < 12; ++ks) {
    bf16x8 qa[2], kt[5];
    qa[0] = *(const bf16x8*)(qb + ks * 32);
    qa[1] = *(const bf16x8*)(qb + 16 * 3072 + ks * 32);
#pragma unroll
    for (int tt = 0; tt < 5; ++tt)
      kt[tt] = *(const bf16x8*)(kb + (size_t)tt * 16 * 384 + ks * 32);
#pragma unroll
    for (int ni = 0; ni < 2; ++ni)
#pragma unroll
      for (int tt = 0; tt < 5; ++tt)
        accs[ni][tt] = __builtin_amdgcn_mfma_f32_16x16x32_bf16(qa[ni], kt[tt], accs[ni][tt], 0, 0, 0);
  }

  // mask t >= 77 (t = tt*16 + lr; only tt==4, lr>=13 invalid)
  if (lr >= 13) {
    accs[0][4] = (f32x4){-3.0e38f, -3.0e38f, -3.0e38f, -3.0e38f};
    accs[1][4] = (f32x4){-3.0e38f, -3.0e38f, -3.0e38f, -3.0e38f};
  }

  // ---------------- softmax + P pack to LDS ----------------
#pragma unroll
  for (int ni = 0; ni < 2; ++ni) {
    f32x4 mx = accs[ni][0];
#pragma unroll
    for (int tt = 1; tt < 5; ++tt) {
      mx.x = fmaxf(mx.x, accs[ni][tt].x);
      mx.y = fmaxf(mx.y, accs[ni][tt].y);
      mx.z = fmaxf(mx.z, accs[ni][tt].z);
      mx.w = fmaxf(mx.w, accs[ni][tt].w);
    }
#pragma unroll
    for (int mk = 1; mk <= 8; mk <<= 1) {
      mx.x = fmaxf(mx.x, __shfl_xor(mx.x, mk));
      mx.y = fmaxf(mx.y, __shfl_xor(mx.y, mk));
      mx.z = fmaxf(mx.z, __shfl_xor(mx.z, mk));
      mx.w = fmaxf(mx.w, __shfl_xor(mx.w, mk));
    }
    f32x4 sm = (f32x4){0.f, 0.f, 0.f, 0.f};
#pragma unroll
    for (int tt = 0; tt < 5; ++tt) {
      f32x4 e;
      e.x = __expf((accs[ni][tt].x - mx.x) * scale);
      e.y = __expf((accs[ni][tt].y - mx.y) * scale);
      e.z = __expf((accs[ni][tt].z - mx.z) * scale);
      e.w = __expf((accs[ni][tt].w - mx.w) * scale);
      accs[ni][tt] = e;
      sm += e;
    }
#pragma unroll
    for (int mk = 1; mk <= 8; mk <<= 1) {
      sm.x += __shfl_xor(sm.x, mk);
      sm.y += __shfl_xor(sm.y, mk);
      sm.z += __shfl_xor(sm.z, mk);
      sm.w += __shfl_xor(sm.w, mk);
    }
    f32x4 inv = (f32x4){1.f / sm.x, 1.f / sm.y, 1.f / sm.z, 1.f / sm.w};
    // write P {h,h,l} at [row][3t..3t+2]; row = ni*16 + lc*4 + comp, t = tt*16+lr
#pragma unroll
    for (int tt = 0; tt < 5; ++tt) {
#pragma unroll
      for (int c = 0; c < 4; ++c) {
        float pv = accs[ni][tt][c] * inv[c];
        int row = ni * 16 + lc * 4 + c;
        int t = tt * 16 + lr;
        u16 hh = f2bf(pv);
        float hf = __uint_as_float((uint32_t)hh << 16);
        u16 ll = f2bf(pv - hf);
        u16* pp = &Pw[row * 256 + 3 * t];
        pp[0] = hh; pp[1] = hh; pp[2] = ll;
      }
    }
  }

  // ---------------- PV ----------------
  f32x4 acco[2][8];
#pragma unroll
  for (int ni = 0; ni < 2; ++ni)
#pragma unroll
    for (int dj = 0; dj < 8; ++dj) acco[ni][dj] = (f32x4){0.f, 0.f, 0.f, 0.f};

  const u16* vb = vpk + (size_t)(b * 8 + h) * 128 * 256 + (size_t)lr * 256 + lc * 8;
  const u16* pb = &Pw[lr * 256 + lc * 8];

  for (int ks = 0; ks < 8; ++ks) {
    bf16x8 pa[2], vv[8];
    pa[0] = *(const bf16x8*)(pb + ks * 32);
    pa[1] = *(const bf16x8*)(pb + 16 * 256 + ks * 32);
#pragma unroll
    for (int dj = 0; dj < 8; ++dj)
      vv[dj] = *(const bf16x8*)(vb + (size_t)dj * 16 * 256 + ks * 32);
#pragma unroll
    for (int ni = 0; ni < 2; ++ni)
#pragma unroll
      for (int dj = 0; dj < 8; ++dj)
        acco[ni][dj] = __builtin_amdgcn_mfma_f32_16x16x32_bf16(pa[ni], vv[dj], acco[ni][dj], 0, 0, 0);
  }

  // ---------------- epilogue: out[b][h*128+d][n], float4 over 4 n ----------
#pragma unroll
  for (int ni = 0; ni < 2; ++ni) {
#pragma unroll
    for (int dj = 0; dj < 8; ++dj) {
      int d = h * 128 + dj * 16 + lr;
      int n = n0 + w * 32 + ni * 16 + lc * 4;
      *(f32x4*)(o + ((size_t)b * 1024 + d) * 1024 + n) = acco[ni][dj];
    }
  }
}

// ---------------------------------------------------------------------------
extern "C" void kernel_launch(void* const* d_in, const int* in_sizes, int n_in,
                              void* d_out, int out_size, void* d_ws, size_t ws_size,
                              hipStream_t stream) {
  const float* Vx  = (const float*)d_in[0];
  const float* Tx  = (const float*)d_in[1];
  const float* Wq  = (const float*)d_in[2];
  const float* bq  = (const float*)d_in[3];
  const float* Wkv = (const float*)d_in[4];
  const float* bkv = (const float*)d_in[5];
  const float* Wp  = (const float*)d_in[6];
  const float* bp  = (const float*)d_in[7];
  float* out = (float*)d_out;

  char* ws = (char*)d_ws;
  const size_t MiB = (size_t)1 << 20;
  // Lifetime-aliased layout (total 223 MiB). Step order:
  //  1 packs (W/Vx/Tx)  2 gemm q  3 gemm kv  4 pack_kt/pack_v
  //  5 pack_x(q->qpk)   6 attn    7 pack_x(attn_out->Xpk)  8 gemm out
  //   [0,  64): q (steps 2-5), then attn_out (6-7)
  //   [64,160): Xpk#1 Vx-pack (1-2), qpk (5-6), Xpk#2 attn-pack (7-8)
  //   [160,166) WqPk (1-2)   [166,178) WkvPk (1-3)  [178,190) TxPk (1-3)
  //   [190,196) WpPk (1-8)   [196,207) kvbuf (3-4)
  //   [207,215) KTpk (4-6)   [215,223) Vpk (4-6)
  float* q        = (float*)(ws + 0);
  float* attn_out = (float*)(ws + 0);
  u16*   Xpk      = (u16*)(ws + 64 * MiB);
  u16*   qpk      = (u16*)(ws + 64 * MiB);
  u16*   WqPk     = (u16*)(ws + 160 * MiB);
  u16*   WkvPk    = (u16*)(ws + 166 * MiB);
  u16*   TxPk     = (u16*)(ws + 178 * MiB);
  u16*   WpPk     = (u16*)(ws + 190 * MiB);
  float* kvbuf    = (float*)(ws + 196 * MiB);
  u16*   KTpk     = (u16*)(ws + 207 * MiB);
  u16*   Vpk      = (u16*)(ws + 215 * MiB);

  pack_w<<<4096, 256, 0, stream>>>(Wq, WqPk);
  pack_w<<<4096, 256, 0, stream>>>(Wp, WpPk);
  pack_w<<<8192, 256, 0, stream>>>(Wkv, WkvPk);
  pack_x<<<dim3(32, 32, 16), 256, 0, stream>>>(Vx, Xpk);
  pack_tx<<<dim3(4, 32, 16), 256, 0, stream>>>(Tx, TxPk);
  gemm_mfma<<<dim3(8, 8, 16), 256, 0, stream>>>(WqPk, Xpk, bq, q);
  gemm_kv_mfma<<<dim3(16, 16), 256, 0, stream>>>(WkvPk, TxPk, bkv, kvbuf);
  pack_kt<<<dim3(8, 16), 256, 0, stream>>>(kvbuf, KTpk);
  pack_v<<<dim3(8, 16), 256, 0, stream>>>(kvbuf, Vpk);
  pack_x<<<dim3(32, 32, 16), 256, 0, stream>>>(q, qpk);
  attn_mfma<<<dim3(8, 8, 16), 256, 0, stream>>>(qpk, KTpk, Vpk, attn_out);
  pack_x<<<dim3(32, 32, 16), 256, 0, stream>>>(attn_out, Xpk);
  gemm_mfma<<<dim3(8, 8, 16), 256, 0, stream>>>(WpPk, Xpk, bp, out);
}

// Round 5
// 740.924 us; speedup vs baseline: 1.3353x; 1.0154x over previous
//
#include <hip/hip_runtime.h>
#include <cstdint>
#include <cstddef>

typedef unsigned short u16;
typedef __bf16 bf16x8 __attribute__((ext_vector_type(8)));
typedef float f32x4 __attribute__((ext_vector_type(4)));

typedef __attribute__((address_space(1))) const void global_cvoid;
typedef __attribute__((address_space(3))) void lds_void;

__device__ __forceinline__ void async16(void* lds, const void* g) {
  __builtin_amdgcn_global_load_lds((global_cvoid*)g, (lds_void*)lds, 16, 0, 0);
}

__device__ __forceinline__ u16 f2bf(float f) {  // RNE fp32 -> bf16 bits
  uint32_t u = __float_as_uint(f);
  return (u16)((u + 0x7fffu + ((u >> 16) & 1u)) >> 16);
}

// Pack 4 fp32 -> 12 u16 {h,l,h} stream (B-side pattern), written as 6 dwords.
__device__ __forceinline__ void pack4_hlh(uint32_t* dst, const float* v) {
  u16 h[4], l[4];
#pragma unroll
  for (int u = 0; u < 4; ++u) {
    h[u] = f2bf(v[u]);
    float hf = __uint_as_float((uint32_t)h[u] << 16);
    l[u] = f2bf(v[u] - hf);
  }
  dst[0] = (uint32_t)h[0] | ((uint32_t)l[0] << 16);
  dst[1] = (uint32_t)h[0] | ((uint32_t)h[1] << 16);
  dst[2] = (uint32_t)l[1] | ((uint32_t)h[1] << 16);
  dst[3] = (uint32_t)h[2] | ((uint32_t)l[2] << 16);
  dst[4] = (uint32_t)h[2] | ((uint32_t)h[3] << 16);
  dst[5] = (uint32_t)l[3] | ((uint32_t)h[3] << 16);
}

// Pack 4 fp32 -> 12 u16 {h,h,l} stream (A-side pattern), 6 dwords.
// Complementary to {h,l,h}: products give h*h + h*l + l*h per value.
__device__ __forceinline__ void pack4_hhl(uint32_t* dst, const float* v) {
  u16 h[4], l[4];
#pragma unroll
  for (int u = 0; u < 4; ++u) {
    h[u] = f2bf(v[u]);
    float hf = __uint_as_float((uint32_t)h[u] << 16);
    l[u] = f2bf(v[u] - hf);
  }
  dst[0] = (uint32_t)h[0] | ((uint32_t)h[0] << 16);
  dst[1] = (uint32_t)l[0] | ((uint32_t)h[1] << 16);
  dst[2] = (uint32_t)h[1] | ((uint32_t)l[1] << 16);
  dst[3] = (uint32_t)h[2] | ((uint32_t)h[2] << 16);
  dst[4] = (uint32_t)l[2] | ((uint32_t)h[3] << 16);
  dst[5] = (uint32_t)h[3] | ((uint32_t)l[3] << 16);
}

// ---------------------------------------------------------------------------
// Pack W (A operand): out[d][3c+{0,1,2}] = {hi, hi, lo} of W[d][c].
// ---------------------------------------------------------------------------
__global__ __launch_bounds__(256) void pack_w(const float* __restrict__ W,
                                              u16* __restrict__ out) {
  int idx = blockIdx.x * 256 + threadIdx.x;
  int d = idx >> 10, c = idx & 1023;
  float f = W[idx];
  u16 h = f2bf(f);
  float hf = __uint_as_float((uint32_t)h << 16);
  u16 l = f2bf(f - hf);
  u16* dst = out + (size_t)d * 3072 + 3 * c;
  dst[0] = h; dst[1] = h; dst[2] = l;
}

// ---------------------------------------------------------------------------
// Pack+transpose X (B operand): out[b][n][3c+{0,1,2}] = {h,l,h} of X[b][c][n].
// (still used for the Vx input pack)
// ---------------------------------------------------------------------------
__global__ __launch_bounds__(256) void pack_x(const float* __restrict__ X,
                                              u16* __restrict__ out) {
  const int b = blockIdx.z, c0 = blockIdx.y * 32, n0 = blockIdx.x * 32;
  __shared__ float tile[32][33];
  const float* src = X + ((size_t)b * 1024 + c0) * 1024 + n0;
  const int tc = threadIdx.x >> 5, tn = threadIdx.x & 31;
#pragma unroll
  for (int i = 0; i < 4; ++i)
    tile[tc + i * 8][tn] = src[(size_t)(tc + i * 8) * 1024 + tn];
  __syncthreads();
  const int nl = threadIdx.x >> 3, cg = (threadIdx.x & 7) * 4;
  float v[4];
#pragma unroll
  for (int u = 0; u < 4; ++u) v[u] = tile[cg + u][nl];
  uint32_t* dst = (uint32_t*)(out + ((size_t)b * 1024 + n0 + nl) * 3072 +
                              (size_t)(c0 + cg) * 3);
  pack4_hlh(dst, v);
}

// ---------------------------------------------------------------------------
// Pack+transpose Tx: Tx[b][1024 c][77 t] -> TxPk[b][128 t][3072] {h,l,h},
// rows t>=77 zeroed. grid (4 t-tiles, 32 c-tiles, 16 b).
// ---------------------------------------------------------------------------
__global__ __launch_bounds__(256) void pack_tx(const float* __restrict__ Tx,
                                               u16* __restrict__ out) {
  const int b = blockIdx.z, c0 = blockIdx.y * 32, t0 = blockIdx.x * 32;
  __shared__ float tile[32][33];
  const float* src = Tx + ((size_t)b * 1024 + c0) * 77;
  const int tc = threadIdx.x >> 5, tn = threadIdx.x & 31;
#pragma unroll
  for (int i = 0; i < 4; ++i) {
    int t = t0 + tn;
    tile[tc + i * 8][tn] = (t < 77) ? src[(size_t)(tc + i * 8) * 77 + t] : 0.f;
  }
  __syncthreads();
  const int nl = threadIdx.x >> 3, cg = (threadIdx.x & 7) * 4;
  float v[4];
#pragma unroll
  for (int u = 0; u < 4; ++u) v[u] = tile[cg + u][nl];
  uint32_t* dst = (uint32_t*)(out + ((size_t)b * 128 + t0 + nl) * 3072 +
                              (size_t)(c0 + cg) * 3);
  pack4_hlh(dst, v);
}

// ---------------------------------------------------------------------------
// K repack for attention: kvbuf K rows [b][h*256+d][80 t] (fp32) ->
// KTpk[(b*8+h)][t][384] = {h,h,l} over d (transposed, d-contiguous).
// grid (8 h, 16 b), 256 threads.
// ---------------------------------------------------------------------------
__global__ __launch_bounds__(256) void pack_kt(const float* __restrict__ kv,
                                               u16* __restrict__ out) {
  const int h = blockIdx.x, b = blockIdx.y;
  __shared__ float sk[128][81];
  const float* src = kv + ((size_t)b * 2048 + h * 256) * 80;
#pragma unroll
  for (int it = 0; it < 40; ++it) {
    int idx = it * 256 + threadIdx.x;  // 0..10239 over [d][t]
    sk[idx / 80][idx % 80] = src[idx];
  }
  __syncthreads();
#pragma unroll
  for (int it = 0; it < 10; ++it) {
    int idx = it * 256 + threadIdx.x;  // 0..2559 over (t, d-group)
    int t = idx >> 5, dg = (idx & 31) * 4;
    float v[4];
#pragma unroll
    for (int u = 0; u < 4; ++u) v[u] = sk[dg + u][t];
    uint32_t* dst = (uint32_t*)(out + ((size_t)(b * 8 + h) * 80 + t) * 384 +
                                (size_t)3 * dg);
    pack4_hhl(dst, v);
  }
}

// ---------------------------------------------------------------------------
// V repack for attention: kvbuf V rows [b][h*256+128+d][80 t] (fp32) ->
// Vpk[(b*8+h)][d][256] = {h,l,h} over t (k' = 3*80 = 240, cols 240..256 = 0).
// grid (8 h, 16 b), 256 threads.
// ---------------------------------------------------------------------------
__global__ __launch_bounds__(256) void pack_v(const float* __restrict__ kv,
                                              u16* __restrict__ out) {
  const int h = blockIdx.x, b = blockIdx.y;
  const float* src = kv + ((size_t)b * 2048 + h * 256 + 128) * 80;
  u16* ob = out + (size_t)(b * 8 + h) * 128 * 256;
#pragma unroll
  for (int it = 0; it < 10; ++it) {
    int idx = it * 256 + threadIdx.x;  // 0..2559 over (d, t-group)
    int d = idx / 20, tg = idx % 20;
    float4 v4 = *(const float4*)(src + (size_t)d * 80 + tg * 4);
    float v[4] = {v4.x, v4.y, v4.z, v4.w};
    uint32_t* dst = (uint32_t*)(ob + (size_t)d * 256 + 12 * tg);
    pack4_hlh(dst, v);
  }
  // zero pad cols [240,256): 128 rows x 16 u16; 256 threads -> 1 store each
  {
    int row = threadIdx.x >> 1, part = threadIdx.x & 1;
    *(uint4*)(ob + (size_t)row * 256 + 240 + part * 8) = make_uint4(0, 0, 0, 0);
  }
}

// ---------------------------------------------------------------------------
// MFMA GEMM (2-phase double-buffered), templated epilogue:
//   OUTMODE 0: Y fp32 [b][d][n] = acc + bias (final projection -> d_out)
//   OUTMODE 1: Y u16  [b][n][3d] {h,l,h} packed (writes qpk directly; the
//              standalone pack_x pass over q is fused away). Lane holds 4
//              consecutive d for one n -> pack4_hlh = one 24B store.
// Body: BK'=64 u16 (2 MFMA k-slices)/step, 48 steps, ONE barrier per step,
// next-tile global_load_lds issued before ds_read+MFMA. LDS 64 KiB, 2 blk/CU.
// ---------------------------------------------------------------------------
template <int OUTMODE>
__global__ __launch_bounds__(256) void gemm_mfma(
    const u16* __restrict__ Apk, const u16* __restrict__ Bpk,
    const float* __restrict__ bias, void* __restrict__ Yv)
{
  const int b  = blockIdx.z;
  const int d0 = blockIdx.y * 128;
  const int n0 = blockIdx.x * 128;
  const int tid  = threadIdx.x;
  const int lane = tid & 63;
  const int w    = tid >> 6;
  const int wm   = w >> 1, wn = w & 1;

  __shared__ __align__(16) char smem[65536];

  const int lr = lane & 15;
  const int lk = (lane >> 4) * 8;

  const u16* Bb = Bpk + (size_t)b * 1024 * 3072;
  const char* gA0 = (const char*)(Apk + ((size_t)(d0 + (w * 2 + 0) * 16 + lr) * 3072 + lk));
  const char* gA1 = (const char*)(Apk + ((size_t)(d0 + (w * 2 + 1) * 16 + lr) * 3072 + lk));
  const char* gB0 = (const char*)(Bb  + ((size_t)(n0 + (w * 2 + 0) * 16 + lr) * 3072 + lk));
  const char* gB1 = (const char*)(Bb  + ((size_t)(n0 + (w * 2 + 1) * 16 + lr) * 3072 + lk));

  auto stage = [&](int p, int ks) {
    char* ba = smem + p * 32768 + (w * 2) * 1024;
    char* bb = ba + 16384;
    const int kb = ks * 128;
#pragma unroll
    for (int k2 = 0; k2 < 2; ++k2) {
      async16(ba + k2 * 8192,        gA0 + kb + k2 * 64);
      async16(ba + k2 * 8192 + 1024, gA1 + kb + k2 * 64);
      async16(bb + k2 * 8192,        gB0 + kb + k2 * 64);
      async16(bb + k2 * 8192 + 1024, gB1 + kb + k2 * 64);
    }
  };

  f32x4 acc[4][4];
#pragma unroll
  for (int i = 0; i < 4; ++i)
#pragma unroll
    for (int j = 0; j < 4; ++j) acc[i][j] = (f32x4){0.f, 0.f, 0.f, 0.f};

  stage(0, 0);
  __syncthreads();

  int p = 0;
  for (int ks = 0; ks < 48; ++ks) {
    if (ks < 47) stage(p ^ 1, ks + 1);   // prefetch next tile (other buffer)
    const char* baseA = smem + p * 32768 + wm * 4096 + lane * 16;
    const char* baseB = smem + p * 32768 + 16384 + wn * 4096 + lane * 16;
#pragma unroll
    for (int k2 = 0; k2 < 2; ++k2) {
      bf16x8 af[4], bfv[4];
#pragma unroll
      for (int i = 0; i < 4; ++i) {
        af[i]  = *(const bf16x8*)(baseA + k2 * 8192 + i * 1024);
        bfv[i] = *(const bf16x8*)(baseB + k2 * 8192 + i * 1024);
      }
#pragma unroll
      for (int i = 0; i < 4; ++i)
#pragma unroll
        for (int j = 0; j < 4; ++j)
          acc[i][j] = __builtin_amdgcn_mfma_f32_16x16x32_bf16(af[i], bfv[j], acc[i][j], 0, 0, 0);
    }
    __syncthreads();   // drains prefetch (vmcnt) AFTER compute; frees buf p
    p ^= 1;
  }

#pragma unroll
  for (int i = 0; i < 4; ++i) {
    const int dbase = d0 + wm * 64 + i * 16 + (lane >> 4) * 4;
    const float4 bv = *(const float4*)(bias + dbase);
#pragma unroll
    for (int j = 0; j < 4; ++j) {
      const int n = n0 + wn * 64 + j * 16 + lr;
      if (OUTMODE == 0) {
        float* yp = (float*)Yv + ((size_t)b * 1024 + dbase) * 1024 + n;
        yp[0]        = acc[i][j].x + bv.x;
        yp[1024]     = acc[i][j].y + bv.y;
        yp[2 * 1024] = acc[i][j].z + bv.z;
        yp[3 * 1024] = acc[i][j].w + bv.w;
      } else {
        float v[4] = {acc[i][j].x + bv.x, acc[i][j].y + bv.y,
                      acc[i][j].z + bv.z, acc[i][j].w + bv.w};
        uint32_t* dst = (uint32_t*)((u16*)Yv +
                                    ((size_t)b * 1024 + n) * 3072 + 3 * dbase);
        pack4_hlh(dst, v);
      }
    }
  }
}

// ---------------------------------------------------------------------------
// KV MFMA GEMM (same 2-phase structure): kv[b][e][t(80pad)] =
// sum Wkv[e][c] Tx[b][c][t] + bkv[e]
// ---------------------------------------------------------------------------
__global__ __launch_bounds__(256) void gemm_kv_mfma(
    const u16* __restrict__ Apk, const u16* __restrict__ Bpk,
    const float* __restrict__ bias, float* __restrict__ Y)
{
  const int b  = blockIdx.y;
  const int d0 = blockIdx.x * 128;
  const int tid  = threadIdx.x;
  const int lane = tid & 63;
  const int w    = tid >> 6;
  const int wm   = w >> 1, wn = w & 1;

  __shared__ __align__(16) char smem[65536];

  const int lr = lane & 15;
  const int lk = (lane >> 4) * 8;

  const u16* Bb = Bpk + (size_t)b * 128 * 3072;
  const char* gA0 = (const char*)(Apk + ((size_t)(d0 + (w * 2 + 0) * 16 + lr) * 3072 + lk));
  const char* gA1 = (const char*)(Apk + ((size_t)(d0 + (w * 2 + 1) * 16 + lr) * 3072 + lk));
  const char* gB0 = (const char*)(Bb  + ((size_t)((w * 2 + 0) * 16 + lr) * 3072 + lk));
  const char* gB1 = (const char*)(Bb  + ((size_t)((w * 2 + 1) * 16 + lr) * 3072 + lk));

  auto stage = [&](int p, int ks) {
    char* ba = smem + p * 32768 + (w * 2) * 1024;
    char* bb = ba + 16384;
    const int kb = ks * 128;
#pragma unroll
    for (int k2 = 0; k2 < 2; ++k2) {
      async16(ba + k2 * 8192,        gA0 + kb + k2 * 64);
      async16(ba + k2 * 8192 + 1024, gA1 + kb + k2 * 64);
      async16(bb + k2 * 8192,        gB0 + kb + k2 * 64);
      async16(bb + k2 * 8192 + 1024, gB1 + kb + k2 * 64);
    }
  };

  f32x4 acc[4][4];
#pragma unroll
  for (int i = 0; i < 4; ++i)
#pragma unroll
    for (int j = 0; j < 4; ++j) acc[i][j] = (f32x4){0.f, 0.f, 0.f, 0.f};

  stage(0, 0);
  __syncthreads();

  int p = 0;
  for (int ks = 0; ks < 48; ++ks) {
    if (ks < 47) stage(p ^ 1, ks + 1);
    const char* baseA = smem + p * 32768 + wm * 4096 + lane * 16;
    const char* baseB = smem + p * 32768 + 16384 + wn * 4096 + lane * 16;
#pragma unroll
    for (int k2 = 0; k2 < 2; ++k2) {
      bf16x8 af[4], bfv[4];
#pragma unroll
      for (int i = 0; i < 4; ++i) {
        af[i]  = *(const bf16x8*)(baseA + k2 * 8192 + i * 1024);
        bfv[i] = *(const bf16x8*)(baseB + k2 * 8192 + i * 1024);
      }
#pragma unroll
      for (int i = 0; i < 4; ++i)
#pragma unroll
        for (int j = 0; j < 4; ++j)
          acc[i][j] = __builtin_amdgcn_mfma_f32_16x16x32_bf16(af[i], bfv[j], acc[i][j], 0, 0, 0);
    }
    __syncthreads();
    p ^= 1;
  }

#pragma unroll
  for (int i = 0; i < 4; ++i) {
    const int dbase = d0 + wm * 64 + i * 16 + (lane >> 4) * 4;
    const float4 bv = *(const float4*)(bias + dbase);
#pragma unroll
    for (int j = 0; j < 4; ++j) {
      const int n = wn * 64 + j * 16 + lr;
      if (n < 80) {
        float* yp = Y + ((size_t)b * 2048 + dbase) * 80 + n;
        yp[0]      = acc[i][j].x + bv.x;
        yp[80]     = acc[i][j].y + bv.y;
        yp[160]    = acc[i][j].z + bv.z;
        yp[240]    = acc[i][j].w + bv.w;
      }
    }
  }
}

// ---------------------------------------------------------------------------
// MFMA attention, fused output pack. Per block: one (b,h), 128 n-rows;
// 4 waves x 32 rows. QK^T and softmax as before (wave-private, no barriers).
// NEW epilogue: instead of fp32 o[b][c][n] (which then needed a pack_x pass),
// the wave stages its 32n x 128d fp32 tile into its (now dead) P-LDS slice,
// re-reads row-wise as f32x4 and writes packed {h,l,h} triples straight to
// Xpk[b][n][3c], c = h*128 + d  (768 B contiguous per n-row, coalesced).
// ---------------------------------------------------------------------------
__global__ __launch_bounds__(256, 2) void attn_mfma(
    const u16* __restrict__ qpk,   // [B][1024 n][3072] {h,l,h}
    const u16* __restrict__ ktpk,  // [B*8][80 t][384]  {h,h,l}
    const u16* __restrict__ vpk,   // [B*8][128 d][256] {h,l,h}, 240..256 = 0
    u16* __restrict__ xout)        // [B][1024 n][3072] {h,l,h} packed
{
  const int b  = blockIdx.z;
  const int h  = blockIdx.y;
  const int n0 = blockIdx.x * 128;
  const int tid  = threadIdx.x;
  const int w    = tid >> 6;
  const int lane = tid & 63;
  const int lr = lane & 15;      // frag row / output col
  const int lc = lane >> 4;      // frag k-chunk / output row group
  const float scale = 0.08838834764831845f;  // 128^-0.5

  __shared__ u16 Plds[4][32 * 256];   // 64 KiB total, wave-private slices
  u16* Pw = &Plds[w][0];

  // zero P pad cols [240,256) for this wave's 32 rows (1 x 16B store/lane)
  {
    int row = lane & 31, part = lane >> 5;
    *(uint4*)&Pw[row * 256 + 240 + part * 8] = make_uint4(0, 0, 0, 0);
  }

  // ---------------- QK^T ----------------
  const u16* qb = qpk + ((size_t)b * 1024 + n0 + w * 32 + lr) * 3072 +
                  384 * h + lc * 8;
  const u16* kb = ktpk + (size_t)(b * 8 + h) * 80 * 384 + (size_t)lr * 384 + lc * 8;

  f32x4 accs[2][5];
#pragma unroll
  for (int ni = 0; ni < 2; ++ni)
#pragma unroll
    for (int tt = 0; tt < 5; ++tt) accs[ni][tt] = (f32x4){0.f, 0.f, 0.f, 0.f};

  for (int ks = 0; ks < 12; ++ks) {
    bf16x8 qa[2], kt[5];
    qa[0] = *(const bf16x8*)(qb + ks * 32);
    qa[1] = *(const bf16x8*)(qb + 16 * 3072 + ks * 32);
#pragma unroll
    for (int tt = 0; tt < 5; ++tt)
      kt[tt] = *(const bf16x8*)(kb + (size_t)tt * 16 * 384 + ks * 32);
#pragma unroll
    for (int ni = 0; ni < 2; ++ni)
#pragma unroll
      for (int tt = 0; tt < 5; ++tt)
        accs[ni][tt] = __builtin_amdgcn_mfma_f32_16x16x32_bf16(qa[ni], kt[tt], accs[ni][tt], 0, 0, 0);
  }

  // mask t >= 77 (t = tt*16 + lr; only tt==4, lr>=13 invalid)
  if (lr >= 13) {
    accs[0][4] = (f32x4){-3.0e38f, -3.0e38f, -3.0e38f, -3.0e38f};
    accs[1][4] = (f32x4){-3.0e38f, -3.0e38f, -3.0e38f, -3.0e38f};
  }

  // ---------------- softmax + P pack to LDS ----------------
#pragma unroll
  for (int ni = 0; ni < 2; ++ni) {
    f32x4 mx = accs[ni][0];
#pragma unroll
    for (int tt = 1; tt < 5; ++tt) {
      mx.x = fmaxf(mx.x, accs[ni][tt].x);
      mx.y = fmaxf(mx.y, accs[ni][tt].y);
      mx.z = fmaxf(mx.z, accs[ni][tt].z);
      mx.w = fmaxf(mx.w, accs[ni][tt].w);
    }
#pragma unroll
    for (int mk = 1; mk <= 8; mk <<= 1) {
      mx.x = fmaxf(mx.x, __shfl_xor(mx.x, mk));
      mx.y = fmaxf(mx.y, __shfl_xor(mx.y, mk));
      mx.z = fmaxf(mx.z, __shfl_xor(mx.z, mk));
      mx.w = fmaxf(mx.w, __shfl_xor(mx.w, mk));
    }
    f32x4 sm = (f32x4){0.f, 0.f, 0.f, 0.f};
#pragma unroll
    for (int tt = 0; tt < 5; ++tt) {
      f32x4 e;
      e.x = __expf((accs[ni][tt].x - mx.x) * scale);
      e.y = __expf((accs[ni][tt].y - mx.y) * scale);
      e.z = __expf((accs[ni][tt].z - mx.z) * scale);
      e.w = __expf((accs[ni][tt].w - mx.w) * scale);
      accs[ni][tt] = e;
      sm += e;
    }
#pragma unroll
    for (int mk = 1; mk <= 8; mk <<= 1) {
      sm.x += __shfl_xor(sm.x, mk);
      sm.y += __shfl_xor(sm.y, mk);
      sm.z += __shfl_xor(sm.z, mk);
      sm.w += __shfl_xor(sm.w, mk);
    }
    f32x4 inv = (f32x4){1.f / sm.x, 1.f / sm.y, 1.f / sm.z, 1.f / sm.w};
    // write P {h,h,l} at [row][3t..3t+2]; row = ni*16 + lc*4 + comp, t = tt*16+lr
#pragma unroll
    for (int tt = 0; tt < 5; ++tt) {
#pragma unroll
      for (int c = 0; c < 4; ++c) {
        float pv = accs[ni][tt][c] * inv[c];
        int row = ni * 16 + lc * 4 + c;
        int t = tt * 16 + lr;
        u16 hh = f2bf(pv);
        float hf = __uint_as_float((uint32_t)hh << 16);
        u16 ll = f2bf(pv - hf);
        u16* pp = &Pw[row * 256 + 3 * t];
        pp[0] = hh; pp[1] = hh; pp[2] = ll;
      }
    }
  }

  // ---------------- PV ----------------
  f32x4 acco[2][8];
#pragma unroll
  for (int ni = 0; ni < 2; ++ni)
#pragma unroll
    for (int dj = 0; dj < 8; ++dj) acco[ni][dj] = (f32x4){0.f, 0.f, 0.f, 0.f};

  const u16* vb = vpk + (size_t)(b * 8 + h) * 128 * 256 + (size_t)lr * 256 + lc * 8;
  const u16* pb = &Pw[lr * 256 + lc * 8];

  for (int ks = 0; ks < 8; ++ks) {
    bf16x8 pa[2], vv[8];
    pa[0] = *(const bf16x8*)(pb + ks * 32);
    pa[1] = *(const bf16x8*)(pb + 16 * 256 + ks * 32);
#pragma unroll
    for (int dj = 0; dj < 8; ++dj)
      vv[dj] = *(const bf16x8*)(vb + (size_t)dj * 16 * 256 + ks * 32);
#pragma unroll
    for (int ni = 0; ni < 2; ++ni)
#pragma unroll
      for (int dj = 0; dj < 8; ++dj)
        acco[ni][dj] = __builtin_amdgcn_mfma_f32_16x16x32_bf16(pa[ni], vv[dj], acco[ni][dj], 0, 0, 0);
  }

  // ---------------- fused epilogue: pack to Xpk[b][n][3c] ----------------
  // Reuse this wave's (dead) P slice as fp32 scratch [32 n][128 d] = 16 KiB.
  // P reads above and these writes are same-wave DS ops -> in-order, no sync.
  float* Pf = (float*)Pw;
#pragma unroll
  for (int ni = 0; ni < 2; ++ni)
#pragma unroll
    for (int dj = 0; dj < 8; ++dj) {
      const int dl = dj * 16 + lr;
#pragma unroll
      for (int c = 0; c < 4; ++c)
        Pf[(ni * 16 + lc * 4 + c) * 128 + dl] = acco[ni][dj][c];
    }

  const int prow = lane >> 5;   // 0..1
  const int pgrp = lane & 31;   // 0..31 (d-group of 4)
#pragma unroll
  for (int r2 = 0; r2 < 16; ++r2) {
    const int row = r2 * 2 + prow;
    f32x4 vv4 = *(const f32x4*)&Pf[row * 128 + pgrp * 4];
    float v[4] = {vv4.x, vv4.y, vv4.z, vv4.w};
    uint32_t* dst = (uint32_t*)(xout +
        ((size_t)b * 1024 + n0 + w * 32 + row) * 3072 + 384 * h + 12 * pgrp);
    pack4_hlh(dst, v);
  }
}

// ---------------------------------------------------------------------------
extern "C" void kernel_launch(void* const* d_in, const int* in_sizes, int n_in,
                              void* d_out, int out_size, void* d_ws, size_t ws_size,
                              hipStream_t stream) {
  const float* Vx  = (const float*)d_in[0];
  const float* Tx  = (const float*)d_in[1];
  const float* Wq  = (const float*)d_in[2];
  const float* bq  = (const float*)d_in[3];
  const float* Wkv = (const float*)d_in[4];
  const float* bkv = (const float*)d_in[5];
  const float* Wp  = (const float*)d_in[6];
  const float* bp  = (const float*)d_in[7];
  float* out = (float*)d_out;

  char* ws = (char*)d_ws;
  const size_t MiB = (size_t)1 << 20;
  // Lifetime-aliased layout (total 239 MiB). Step order:
  //  1 packs (W/Vx/Tx)   2 gemm#1 -> qpk (fused pack)   3 gemm kv
  //  4 pack_kt/pack_v    5 attn -> Xpk (fused pack)     6 gemm#2 -> out
  //   [0,  96): Xpk  — Vx-pack (1-2), then attn-out pack (5-6)
  //   [96,192): qpk  — gemm#1 out (2), attn in (5)
  //   [192,198) WqPk (1-2)     [198,210) WkvPk (1-3)
  //   [192,200) KTpk (4-5)     [200,208) Vpk (4-5)   — over dead Wq/Wkv
  //   [210,222) TxPk (1-3)     [222,233) kvbuf (3-4)  [233,239) WpPk (1-6)
  u16*   Xpk      = (u16*)(ws + 0);
  u16*   qpk      = (u16*)(ws + 96 * MiB);
  u16*   WqPk     = (u16*)(ws + 192 * MiB);
  u16*   KTpk     = (u16*)(ws + 192 * MiB);
  u16*   WkvPk    = (u16*)(ws + 198 * MiB);
  u16*   Vpk      = (u16*)(ws + 200 * MiB);
  u16*   TxPk     = (u16*)(ws + 210 * MiB);
  float* kvbuf    = (float*)(ws + 222 * MiB);
  u16*   WpPk     = (u16*)(ws + 233 * MiB);

  pack_w<<<4096, 256, 0, stream>>>(Wq, WqPk);
  pack_w<<<4096, 256, 0, stream>>>(Wp, WpPk);
  pack_w<<<8192, 256, 0, stream>>>(Wkv, WkvPk);
  pack_x<<<dim3(32, 32, 16), 256, 0, stream>>>(Vx, Xpk);
  pack_tx<<<dim3(4, 32, 16), 256, 0, stream>>>(Tx, TxPk);
  gemm_mfma<1><<<dim3(8, 8, 16), 256, 0, stream>>>(WqPk, Xpk, bq, qpk);
  gemm_kv_mfma<<<dim3(16, 16), 256, 0, stream>>>(WkvPk, TxPk, bkv, kvbuf);
  pack_kt<<<dim3(8, 16), 256, 0, stream>>>(kvbuf, KTpk);
  pack_v<<<dim3(8, 16), 256, 0, stream>>>(kvbuf, Vpk);
  attn_mfma<<<dim3(8, 8, 16), 256, 0, stream>>>(qpk, KTpk, Vpk, Xpk);
  gemm_mfma<0><<<dim3(8, 8, 16), 256, 0, stream>>>(WpPk, Xpk, bp, out);
}

// Round 6
// 694.286 us; speedup vs baseline: 1.4250x; 1.0672x over previous
//
#include <hip/hip_runtime.h>
#include <cstdint>
#include <cstddef>

typedef unsigned short u16;
typedef __bf16 bf16x8 __attribute__((ext_vector_type(8)));
typedef float f32x4 __attribute__((ext_vector_type(4)));

typedef __attribute__((address_space(1))) const void global_cvoid;
typedef __attribute__((address_space(3))) void lds_void;

__device__ __forceinline__ void async16(void* lds, const void* g) {
  __builtin_amdgcn_global_load_lds((global_cvoid*)g, (lds_void*)lds, 16, 0, 0);
}

__device__ __forceinline__ u16 f2bf(float f) {  // RNE fp32 -> bf16 bits
  uint32_t u = __float_as_uint(f);
  return (u16)((u + 0x7fffu + ((u >> 16) & 1u)) >> 16);
}

// Pack 4 fp32 -> 12 u16 {h,l,h} stream (B-side pattern), written as 6 dwords.
__device__ __forceinline__ void pack4_hlh(uint32_t* dst, const float* v) {
  u16 h[4], l[4];
#pragma unroll
  for (int u = 0; u < 4; ++u) {
    h[u] = f2bf(v[u]);
    float hf = __uint_as_float((uint32_t)h[u] << 16);
    l[u] = f2bf(v[u] - hf);
  }
  dst[0] = (uint32_t)h[0] | ((uint32_t)l[0] << 16);
  dst[1] = (uint32_t)h[0] | ((uint32_t)h[1] << 16);
  dst[2] = (uint32_t)l[1] | ((uint32_t)h[1] << 16);
  dst[3] = (uint32_t)h[2] | ((uint32_t)l[2] << 16);
  dst[4] = (uint32_t)h[2] | ((uint32_t)h[3] << 16);
  dst[5] = (uint32_t)l[3] | ((uint32_t)h[3] << 16);
}

// Pack 4 fp32 -> 12 u16 {h,h,l} stream (A-side pattern), 6 dwords.
// Complementary to {h,l,h}: products give h*h + h*l + l*h per value.
__device__ __forceinline__ void pack4_hhl(uint32_t* dst, const float* v) {
  u16 h[4], l[4];
#pragma unroll
  for (int u = 0; u < 4; ++u) {
    h[u] = f2bf(v[u]);
    float hf = __uint_as_float((uint32_t)h[u] << 16);
    l[u] = f2bf(v[u] - hf);
  }
  dst[0] = (uint32_t)h[0] | ((uint32_t)h[0] << 16);
  dst[1] = (uint32_t)l[0] | ((uint32_t)h[1] << 16);
  dst[2] = (uint32_t)h[1] | ((uint32_t)l[1] << 16);
  dst[3] = (uint32_t)h[2] | ((uint32_t)h[2] << 16);
  dst[4] = (uint32_t)l[2] | ((uint32_t)h[3] << 16);
  dst[5] = (uint32_t)h[3] | ((uint32_t)l[3] << 16);
}

// ---------------------------------------------------------------------------
// Pack W (A operand): out[d][3c+{0,1,2}] = {hi, hi, lo} of W[d][c].
// ---------------------------------------------------------------------------
__global__ __launch_bounds__(256) void pack_w(const float* __restrict__ W,
                                              u16* __restrict__ out) {
  int idx = blockIdx.x * 256 + threadIdx.x;
  int d = idx >> 10, c = idx & 1023;
  float f = W[idx];
  u16 h = f2bf(f);
  float hf = __uint_as_float((uint32_t)h << 16);
  u16 l = f2bf(f - hf);
  u16* dst = out + (size_t)d * 3072 + 3 * c;
  dst[0] = h; dst[1] = h; dst[2] = l;
}

// ---------------------------------------------------------------------------
// Pack+transpose X (B operand): out[b][n][3c+{0,1,2}] = {h,l,h} of X[b][c][n].
// (still used for the Vx input pack)
// ---------------------------------------------------------------------------
__global__ __launch_bounds__(256) void pack_x(const float* __restrict__ X,
                                              u16* __restrict__ out) {
  const int b = blockIdx.z, c0 = blockIdx.y * 32, n0 = blockIdx.x * 32;
  __shared__ float tile[32][33];
  const float* src = X + ((size_t)b * 1024 + c0) * 1024 + n0;
  const int tc = threadIdx.x >> 5, tn = threadIdx.x & 31;
#pragma unroll
  for (int i = 0; i < 4; ++i)
    tile[tc + i * 8][tn] = src[(size_t)(tc + i * 8) * 1024 + tn];
  __syncthreads();
  const int nl = threadIdx.x >> 3, cg = (threadIdx.x & 7) * 4;
  float v[4];
#pragma unroll
  for (int u = 0; u < 4; ++u) v[u] = tile[cg + u][nl];
  uint32_t* dst = (uint32_t*)(out + ((size_t)b * 1024 + n0 + nl) * 3072 +
                              (size_t)(c0 + cg) * 3);
  pack4_hlh(dst, v);
}

// ---------------------------------------------------------------------------
// Pack+transpose Tx: Tx[b][1024 c][77 t] -> TxPk[b][128 t][3072] {h,l,h},
// rows t>=77 zeroed. grid (4 t-tiles, 32 c-tiles, 16 b).
// ---------------------------------------------------------------------------
__global__ __launch_bounds__(256) void pack_tx(const float* __restrict__ Tx,
                                               u16* __restrict__ out) {
  const int b = blockIdx.z, c0 = blockIdx.y * 32, t0 = blockIdx.x * 32;
  __shared__ float tile[32][33];
  const float* src = Tx + ((size_t)b * 1024 + c0) * 77;
  const int tc = threadIdx.x >> 5, tn = threadIdx.x & 31;
#pragma unroll
  for (int i = 0; i < 4; ++i) {
    int t = t0 + tn;
    tile[tc + i * 8][tn] = (t < 77) ? src[(size_t)(tc + i * 8) * 77 + t] : 0.f;
  }
  __syncthreads();
  const int nl = threadIdx.x >> 3, cg = (threadIdx.x & 7) * 4;
  float v[4];
#pragma unroll
  for (int u = 0; u < 4; ++u) v[u] = tile[cg + u][nl];
  uint32_t* dst = (uint32_t*)(out + ((size_t)b * 128 + t0 + nl) * 3072 +
                              (size_t)(c0 + cg) * 3);
  pack4_hlh(dst, v);
}

// ---------------------------------------------------------------------------
// K repack for attention: kvbuf K rows [b][h*256+d][80 t] (fp32) ->
// KTpk[(b*8+h)][t][384] = {h,h,l} over d (transposed, d-contiguous).
// grid (8 h, 16 b), 256 threads.
// ---------------------------------------------------------------------------
__global__ __launch_bounds__(256) void pack_kt(const float* __restrict__ kv,
                                               u16* __restrict__ out) {
  const int h = blockIdx.x, b = blockIdx.y;
  __shared__ float sk[128][81];
  const float* src = kv + ((size_t)b * 2048 + h * 256) * 80;
#pragma unroll
  for (int it = 0; it < 40; ++it) {
    int idx = it * 256 + threadIdx.x;  // 0..10239 over [d][t]
    sk[idx / 80][idx % 80] = src[idx];
  }
  __syncthreads();
#pragma unroll
  for (int it = 0; it < 10; ++it) {
    int idx = it * 256 + threadIdx.x;  // 0..2559 over (t, d-group)
    int t = idx >> 5, dg = (idx & 31) * 4;
    float v[4];
#pragma unroll
    for (int u = 0; u < 4; ++u) v[u] = sk[dg + u][t];
    uint32_t* dst = (uint32_t*)(out + ((size_t)(b * 8 + h) * 80 + t) * 384 +
                                (size_t)3 * dg);
    pack4_hhl(dst, v);
  }
}

// ---------------------------------------------------------------------------
// V repack for attention: kvbuf V rows [b][h*256+128+d][80 t] (fp32) ->
// Vpk[(b*8+h)][d][256] = {h,l,h} over t (k' = 3*80 = 240, cols 240..256 = 0).
// grid (8 h, 16 b), 256 threads.
// ---------------------------------------------------------------------------
__global__ __launch_bounds__(256) void pack_v(const float* __restrict__ kv,
                                              u16* __restrict__ out) {
  const int h = blockIdx.x, b = blockIdx.y;
  const float* src = kv + ((size_t)b * 2048 + h * 256 + 128) * 80;
  u16* ob = out + (size_t)(b * 8 + h) * 128 * 256;
#pragma unroll
  for (int it = 0; it < 10; ++it) {
    int idx = it * 256 + threadIdx.x;  // 0..2559 over (d, t-group)
    int d = idx / 20, tg = idx % 20;
    float4 v4 = *(const float4*)(src + (size_t)d * 80 + tg * 4);
    float v[4] = {v4.x, v4.y, v4.z, v4.w};
    uint32_t* dst = (uint32_t*)(ob + (size_t)d * 256 + 12 * tg);
    pack4_hlh(dst, v);
  }
  // zero pad cols [240,256): 128 rows x 16 u16; 256 threads -> 1 store each
  {
    int row = threadIdx.x >> 1, part = threadIdx.x & 1;
    *(uint4*)(ob + (size_t)row * 256 + 240 + part * 8) = make_uint4(0, 0, 0, 0);
  }
}

// ---------------------------------------------------------------------------
// MFMA GEMM, counted-vmcnt 2-deep pipeline (T4). Per K-step (64 u16):
//   s_waitcnt vmcnt(8)   <- wait ONLY for the tile about to be consumed
//                           (issued a full iteration earlier); the younger
//                           prefetch stays in flight across the barrier.
//   s_barrier            <- all waves' loads for this tile retired
//   ds_read + 32 MFMA    <- compiler inserts lgkmcnt before consumers
//   s_barrier            <- all reads of this buffer complete
//   stage(tile ks+2)     <- overwrite the just-freed buffer
// Epilogue templated: OUTMODE 0 = fp32 [b][d][n]+bias; OUTMODE 1 = packed
// u16 {h,l,h} qpk [b][n][3d]. LDS 64 KiB (2 bufs), 2 blocks/CU.
// ---------------------------------------------------------------------------
template <int OUTMODE>
__global__ __launch_bounds__(256) void gemm_mfma(
    const u16* __restrict__ Apk, const u16* __restrict__ Bpk,
    const float* __restrict__ bias, void* __restrict__ Yv)
{
  const int b  = blockIdx.z;
  const int d0 = blockIdx.y * 128;
  const int n0 = blockIdx.x * 128;
  const int tid  = threadIdx.x;
  const int lane = tid & 63;
  const int w    = tid >> 6;
  const int wm   = w >> 1, wn = w & 1;

  __shared__ __align__(16) char smem[65536];

  const int lr = lane & 15;
  const int lk = (lane >> 4) * 8;

  const u16* Bb = Bpk + (size_t)b * 1024 * 3072;
  const char* gA0 = (const char*)(Apk + ((size_t)(d0 + (w * 2 + 0) * 16 + lr) * 3072 + lk));
  const char* gA1 = (const char*)(Apk + ((size_t)(d0 + (w * 2 + 1) * 16 + lr) * 3072 + lk));
  const char* gB0 = (const char*)(Bb  + ((size_t)(n0 + (w * 2 + 0) * 16 + lr) * 3072 + lk));
  const char* gB1 = (const char*)(Bb  + ((size_t)(n0 + (w * 2 + 1) * 16 + lr) * 3072 + lk));

  // stage tile ks into buffer p: 8 x global_load_lds (16B/lane) per wave
  auto stage = [&](int p, int ks) {
    char* ba = smem + p * 32768 + (w * 2) * 1024;
    char* bb = ba + 16384;
    const int kb = ks * 128;
#pragma unroll
    for (int k2 = 0; k2 < 2; ++k2) {
      async16(ba + k2 * 8192,        gA0 + kb + k2 * 64);
      async16(ba + k2 * 8192 + 1024, gA1 + kb + k2 * 64);
      async16(bb + k2 * 8192,        gB0 + kb + k2 * 64);
      async16(bb + k2 * 8192 + 1024, gB1 + kb + k2 * 64);
    }
  };

  f32x4 acc[4][4];
#pragma unroll
  for (int i = 0; i < 4; ++i)
#pragma unroll
    for (int j = 0; j < 4; ++j) acc[i][j] = (f32x4){0.f, 0.f, 0.f, 0.f};

  stage(0, 0);
  stage(1, 1);

  for (int ks = 0; ks < 48; ++ks) {
    // wait for tile ks only (8 loads of tile ks+1 may stay outstanding)
    if (ks < 47) asm volatile("s_waitcnt vmcnt(8)" ::: "memory");
    else         asm volatile("s_waitcnt vmcnt(0)" ::: "memory");
    __builtin_amdgcn_s_barrier();

    const int p = ks & 1;
    const char* baseA = smem + p * 32768 + wm * 4096 + lane * 16;
    const char* baseB = smem + p * 32768 + 16384 + wn * 4096 + lane * 16;
#pragma unroll
    for (int k2 = 0; k2 < 2; ++k2) {
      bf16x8 af[4], bfv[4];
#pragma unroll
      for (int i = 0; i < 4; ++i) {
        af[i]  = *(const bf16x8*)(baseA + k2 * 8192 + i * 1024);
        bfv[i] = *(const bf16x8*)(baseB + k2 * 8192 + i * 1024);
      }
#pragma unroll
      for (int i = 0; i < 4; ++i)
#pragma unroll
        for (int j = 0; j < 4; ++j)
          acc[i][j] = __builtin_amdgcn_mfma_f32_16x16x32_bf16(af[i], bfv[j], acc[i][j], 0, 0, 0);
    }

    asm volatile("" ::: "memory");
    __builtin_amdgcn_s_barrier();   // all reads of buf p done in every wave
    if (ks + 2 < 48) stage(p, ks + 2);  // overwrite freed buffer
  }

#pragma unroll
  for (int i = 0; i < 4; ++i) {
    const int dbase = d0 + wm * 64 + i * 16 + (lane >> 4) * 4;
    const float4 bv = *(const float4*)(bias + dbase);
#pragma unroll
    for (int j = 0; j < 4; ++j) {
      const int n = n0 + wn * 64 + j * 16 + lr;
      if (OUTMODE == 0) {
        float* yp = (float*)Yv + ((size_t)b * 1024 + dbase) * 1024 + n;
        yp[0]        = acc[i][j].x + bv.x;
        yp[1024]     = acc[i][j].y + bv.y;
        yp[2 * 1024] = acc[i][j].z + bv.z;
        yp[3 * 1024] = acc[i][j].w + bv.w;
      } else {
        float v[4] = {acc[i][j].x + bv.x, acc[i][j].y + bv.y,
                      acc[i][j].z + bv.z, acc[i][j].w + bv.w};
        uint32_t* dst = (uint32_t*)((u16*)Yv +
                                    ((size_t)b * 1024 + n) * 3072 + 3 * dbase);
        pack4_hlh(dst, v);
      }
    }
  }
}

// ---------------------------------------------------------------------------
// KV MFMA GEMM, same counted-vmcnt 2-deep pipeline.
// kv[b][e][t(80pad)] = sum Wkv[e][c] Tx[b][c][t] + bkv[e]
// ---------------------------------------------------------------------------
__global__ __launch_bounds__(256) void gemm_kv_mfma(
    const u16* __restrict__ Apk, const u16* __restrict__ Bpk,
    const float* __restrict__ bias, float* __restrict__ Y)
{
  const int b  = blockIdx.y;
  const int d0 = blockIdx.x * 128;
  const int tid  = threadIdx.x;
  const int lane = tid & 63;
  const int w    = tid >> 6;
  const int wm   = w >> 1, wn = w & 1;

  __shared__ __align__(16) char smem[65536];

  const int lr = lane & 15;
  const int lk = (lane >> 4) * 8;

  const u16* Bb = Bpk + (size_t)b * 128 * 3072;
  const char* gA0 = (const char*)(Apk + ((size_t)(d0 + (w * 2 + 0) * 16 + lr) * 3072 + lk));
  const char* gA1 = (const char*)(Apk + ((size_t)(d0 + (w * 2 + 1) * 16 + lr) * 3072 + lk));
  const char* gB0 = (const char*)(Bb  + ((size_t)((w * 2 + 0) * 16 + lr) * 3072 + lk));
  const char* gB1 = (const char*)(Bb  + ((size_t)((w * 2 + 1) * 16 + lr) * 3072 + lk));

  auto stage = [&](int p, int ks) {
    char* ba = smem + p * 32768 + (w * 2) * 1024;
    char* bb = ba + 16384;
    const int kb = ks * 128;
#pragma unroll
    for (int k2 = 0; k2 < 2; ++k2) {
      async16(ba + k2 * 8192,        gA0 + kb + k2 * 64);
      async16(ba + k2 * 8192 + 1024, gA1 + kb + k2 * 64);
      async16(bb + k2 * 8192,        gB0 + kb + k2 * 64);
      async16(bb + k2 * 8192 + 1024, gB1 + kb + k2 * 64);
    }
  };

  f32x4 acc[4][4];
#pragma unroll
  for (int i = 0; i < 4; ++i)
#pragma unroll
    for (int j = 0; j < 4; ++j) acc[i][j] = (f32x4){0.f, 0.f, 0.f, 0.f};

  stage(0, 0);
  stage(1, 1);

  for (int ks = 0; ks < 48; ++ks) {
    if (ks < 47) asm volatile("s_waitcnt vmcnt(8)" ::: "memory");
    else         asm volatile("s_waitcnt vmcnt(0)" ::: "memory");
    __builtin_amdgcn_s_barrier();

    const int p = ks & 1;
    const char* baseA = smem + p * 32768 + wm * 4096 + lane * 16;
    const char* baseB = smem + p * 32768 + 16384 + wn * 4096 + lane * 16;
#pragma unroll
    for (int k2 = 0; k2 < 2; ++k2) {
      bf16x8 af[4], bfv[4];
#pragma unroll
      for (int i = 0; i < 4; ++i) {
        af[i]  = *(const bf16x8*)(baseA + k2 * 8192 + i * 1024);
        bfv[i] = *(const bf16x8*)(baseB + k2 * 8192 + i * 1024);
      }
#pragma unroll
      for (int i = 0; i < 4; ++i)
#pragma unroll
        for (int j = 0; j < 4; ++j)
          acc[i][j] = __builtin_amdgcn_mfma_f32_16x16x32_bf16(af[i], bfv[j], acc[i][j], 0, 0, 0);
    }

    asm volatile("" ::: "memory");
    __builtin_amdgcn_s_barrier();
    if (ks + 2 < 48) stage(p, ks + 2);
  }

#pragma unroll
  for (int i = 0; i < 4; ++i) {
    const int dbase = d0 + wm * 64 + i * 16 + (lane >> 4) * 4;
    const float4 bv = *(const float4*)(bias + dbase);
#pragma unroll
    for (int j = 0; j < 4; ++j) {
      const int n = wn * 64 + j * 16 + lr;
      if (n < 80) {
        float* yp = Y + ((size_t)b * 2048 + dbase) * 80 + n;
        yp[0]      = acc[i][j].x + bv.x;
        yp[80]     = acc[i][j].y + bv.y;
        yp[160]    = acc[i][j].z + bv.z;
        yp[240]    = acc[i][j].w + bv.w;
      }
    }
  }
}

// ---------------------------------------------------------------------------
// MFMA attention, fused output pack. Per block: one (b,h), 128 n-rows;
// 4 waves x 32 rows. QK^T and softmax wave-private (no barriers).
// Epilogue stages the wave's 32n x 128d fp32 tile into its dead P-LDS slice,
// re-reads row-wise as f32x4 and writes packed {h,l,h} triples straight to
// Xpk[b][n][3c], c = h*128 + d  (768 B contiguous per n-row, coalesced).
// ---------------------------------------------------------------------------
__global__ __launch_bounds__(256, 2) void attn_mfma(
    const u16* __restrict__ qpk,   // [B][1024 n][3072] {h,l,h}
    const u16* __restrict__ ktpk,  // [B*8][80 t][384]  {h,h,l}
    const u16* __restrict__ vpk,   // [B*8][128 d][256] {h,l,h}, 240..256 = 0
    u16* __restrict__ xout)        // [B][1024 n][3072] {h,l,h} packed
{
  const int b  = blockIdx.z;
  const int h  = blockIdx.y;
  const int n0 = blockIdx.x * 128;
  const int tid  = threadIdx.x;
  const int w    = tid >> 6;
  const int lane = tid & 63;
  const int lr = lane & 15;      // frag row / output col
  const int lc = lane >> 4;      // frag k-chunk / output row group
  const float scale = 0.08838834764831845f;  // 128^-0.5

  __shared__ u16 Plds[4][32 * 256];   // 64 KiB total, wave-private slices
  u16* Pw = &Plds[w][0];

  // zero P pad cols [240,256) for this wave's 32 rows (1 x 16B store/lane)
  {
    int row = lane & 31, part = lane >> 5;
    *(uint4*)&Pw[row * 256 + 240 + part * 8] = make_uint4(0, 0, 0, 0);
  }

  // ---------------- QK^T ----------------
  const u16* qb = qpk + ((size_t)b * 1024 + n0 + w * 32 + lr) * 3072 +
                  384 * h + lc * 8;
  const u16* kb = ktpk + (size_t)(b * 8 + h) * 80 * 384 + (size_t)lr * 384 + lc * 8;

  f32x4 accs[2][5];
#pragma unroll
  for (int ni = 0; ni < 2; ++ni)
#pragma unroll
    for (int tt = 0; tt < 5; ++tt) accs[ni][tt] = (f32x4){0.f, 0.f, 0.f, 0.f};

  for (int ks = 0; ks < 12; ++ks) {
    bf16x8 qa[2], kt[5];
    qa[0] = *(const bf16x8*)(qb + ks * 32);
    qa[1] = *(const bf16x8*)(qb + 16 * 3072 + ks * 32);
#pragma unroll
    for (int tt = 0; tt < 5; ++tt)
      kt[tt] = *(const bf16x8*)(kb + (size_t)tt * 16 * 384 + ks * 32);
#pragma unroll
    for (int ni = 0; ni < 2; ++ni)
#pragma unroll
      for (int tt = 0; tt < 5; ++tt)
        accs[ni][tt] = __builtin_amdgcn_mfma_f32_16x16x32_bf16(qa[ni], kt[tt], accs[ni][tt], 0, 0, 0);
  }

  // mask t >= 77 (t = tt*16 + lr; only tt==4, lr>=13 invalid)
  if (lr >= 13) {
    accs[0][4] = (f32x4){-3.0e38f, -3.0e38f, -3.0e38f, -3.0e38f};
    accs[1][4] = (f32x4){-3.0e38f, -3.0e38f, -3.0e38f, -3.0e38f};
  }

  // ---------------- softmax + P pack to LDS ----------------
#pragma unroll
  for (int ni = 0; ni < 2; ++ni) {
    f32x4 mx = accs[ni][0];
#pragma unroll
    for (int tt = 1; tt < 5; ++tt) {
      mx.x = fmaxf(mx.x, accs[ni][tt].x);
      mx.y = fmaxf(mx.y, accs[ni][tt].y);
      mx.z = fmaxf(mx.z, accs[ni][tt].z);
      mx.w = fmaxf(mx.w, accs[ni][tt].w);
    }
#pragma unroll
    for (int mk = 1; mk <= 8; mk <<= 1) {
      mx.x = fmaxf(mx.x, __shfl_xor(mx.x, mk));
      mx.y = fmaxf(mx.y, __shfl_xor(mx.y, mk));
      mx.z = fmaxf(mx.z, __shfl_xor(mx.z, mk));
      mx.w = fmaxf(mx.w, __shfl_xor(mx.w, mk));
    }
    f32x4 sm = (f32x4){0.f, 0.f, 0.f, 0.f};
#pragma unroll
    for (int tt = 0; tt < 5; ++tt) {
      f32x4 e;
      e.x = __expf((accs[ni][tt].x - mx.x) * scale);
      e.y = __expf((accs[ni][tt].y - mx.y) * scale);
      e.z = __expf((accs[ni][tt].z - mx.z) * scale);
      e.w = __expf((accs[ni][tt].w - mx.w) * scale);
      accs[ni][tt] = e;
      sm += e;
    }
#pragma unroll
    for (int mk = 1; mk <= 8; mk <<= 1) {
      sm.x += __shfl_xor(sm.x, mk);
      sm.y += __shfl_xor(sm.y, mk);
      sm.z += __shfl_xor(sm.z, mk);
      sm.w += __shfl_xor(sm.w, mk);
    }
    f32x4 inv = (f32x4){1.f / sm.x, 1.f / sm.y, 1.f / sm.z, 1.f / sm.w};
    // write P {h,h,l} at [row][3t..3t+2]; row = ni*16 + lc*4 + comp, t = tt*16+lr
#pragma unroll
    for (int tt = 0; tt < 5; ++tt) {
#pragma unroll
      for (int c = 0; c < 4; ++c) {
        float pv = accs[ni][tt][c] * inv[c];
        int row = ni * 16 + lc * 4 + c;
        int t = tt * 16 + lr;
        u16 hh = f2bf(pv);
        float hf = __uint_as_float((uint32_t)hh << 16);
        u16 ll = f2bf(pv - hf);
        u16* pp = &Pw[row * 256 + 3 * t];
        pp[0] = hh; pp[1] = hh; pp[2] = ll;
      }
    }
  }

  // ---------------- PV ----------------
  f32x4 acco[2][8];
#pragma unroll
  for (int ni = 0; ni < 2; ++ni)
#pragma unroll
    for (int dj = 0; dj < 8; ++dj) acco[ni][dj] = (f32x4){0.f, 0.f, 0.f, 0.f};

  const u16* vb = vpk + (size_t)(b * 8 + h) * 128 * 256 + (size_t)lr * 256 + lc * 8;
  const u16* pb = &Pw[lr * 256 + lc * 8];

  for (int ks = 0; ks < 8; ++ks) {
    bf16x8 pa[2], vv[8];
    pa[0] = *(const bf16x8*)(pb + ks * 32);
    pa[1] = *(const bf16x8*)(pb + 16 * 256 + ks * 32);
#pragma unroll
    for (int dj = 0; dj < 8; ++dj)
      vv[dj] = *(const bf16x8*)(vb + (size_t)dj * 16 * 256 + ks * 32);
#pragma unroll
    for (int ni = 0; ni < 2; ++ni)
#pragma unroll
      for (int dj = 0; dj < 8; ++dj)
        acco[ni][dj] = __builtin_amdgcn_mfma_f32_16x16x32_bf16(pa[ni], vv[dj], acco[ni][dj], 0, 0, 0);
  }

  // ---------------- fused epilogue: pack to Xpk[b][n][3c] ----------------
  // Reuse this wave's (dead) P slice as fp32 scratch [32 n][128 d] = 16 KiB.
  // P reads above and these writes are same-wave DS ops -> in-order, no sync.
  float* Pf = (float*)Pw;
#pragma unroll
  for (int ni = 0; ni < 2; ++ni)
#pragma unroll
    for (int dj = 0; dj < 8; ++dj) {
      const int dl = dj * 16 + lr;
#pragma unroll
      for (int c = 0; c < 4; ++c)
        Pf[(ni * 16 + lc * 4 + c) * 128 + dl] = acco[ni][dj][c];
    }

  const int prow = lane >> 5;   // 0..1
  const int pgrp = lane & 31;   // 0..31 (d-group of 4)
#pragma unroll
  for (int r2 = 0; r2 < 16; ++r2) {
    const int row = r2 * 2 + prow;
    f32x4 vv4 = *(const f32x4*)&Pf[row * 128 + pgrp * 4];
    float v[4] = {vv4.x, vv4.y, vv4.z, vv4.w};
    uint32_t* dst = (uint32_t*)(xout +
        ((size_t)b * 1024 + n0 + w * 32 + row) * 3072 + 384 * h + 12 * pgrp);
    pack4_hlh(dst, v);
  }
}

// ---------------------------------------------------------------------------
extern "C" void kernel_launch(void* const* d_in, const int* in_sizes, int n_in,
                              void* d_out, int out_size, void* d_ws, size_t ws_size,
                              hipStream_t stream) {
  const float* Vx  = (const float*)d_in[0];
  const float* Tx  = (const float*)d_in[1];
  const float* Wq  = (const float*)d_in[2];
  const float* bq  = (const float*)d_in[3];
  const float* Wkv = (const float*)d_in[4];
  const float* bkv = (const float*)d_in[5];
  const float* Wp  = (const float*)d_in[6];
  const float* bp  = (const float*)d_in[7];
  float* out = (float*)d_out;

  char* ws = (char*)d_ws;
  const size_t MiB = (size_t)1 << 20;
  // Lifetime-aliased layout (total 239 MiB). Step order:
  //  1 packs (W/Vx/Tx)   2 gemm#1 -> qpk (fused pack)   3 gemm kv
  //  4 pack_kt/pack_v    5 attn -> Xpk (fused pack)     6 gemm#2 -> out
  //   [0,  96): Xpk  — Vx-pack (1-2), then attn-out pack (5-6)
  //   [96,192): qpk  — gemm#1 out (2), attn in (5)
  //   [192,198) WqPk (1-2)     [198,210) WkvPk (1-3)
  //   [192,200) KTpk (4-5)     [200,208) Vpk (4-5)   — over dead Wq/Wkv
  //   [210,222) TxPk (1-3)     [222,233) kvbuf (3-4)  [233,239) WpPk (1-6)
  u16*   Xpk      = (u16*)(ws + 0);
  u16*   qpk      = (u16*)(ws + 96 * MiB);
  u16*   WqPk     = (u16*)(ws + 192 * MiB);
  u16*   KTpk     = (u16*)(ws + 192 * MiB);
  u16*   WkvPk    = (u16*)(ws + 198 * MiB);
  u16*   Vpk      = (u16*)(ws + 200 * MiB);
  u16*   TxPk     = (u16*)(ws + 210 * MiB);
  float* kvbuf    = (float*)(ws + 222 * MiB);
  u16*   WpPk     = (u16*)(ws + 233 * MiB);

  pack_w<<<4096, 256, 0, stream>>>(Wq, WqPk);
  pack_w<<<4096, 256, 0, stream>>>(Wp, WpPk);
  pack_w<<<8192, 256, 0, stream>>>(Wkv, WkvPk);
  pack_x<<<dim3(32, 32, 16), 256, 0, stream>>>(Vx, Xpk);
  pack_tx<<<dim3(4, 32, 16), 256, 0, stream>>>(Tx, TxPk);
  gemm_mfma<1><<<dim3(8, 8, 16), 256, 0, stream>>>(WqPk, Xpk, bq, qpk);
  gemm_kv_mfma<<<dim3(16, 16), 256, 0, stream>>>(WkvPk, TxPk, bkv, kvbuf);
  pack_kt<<<dim3(8, 16), 256, 0, stream>>>(kvbuf, KTpk);
  pack_v<<<dim3(8, 16), 256, 0, stream>>>(kvbuf, Vpk);
  attn_mfma<<<dim3(8, 8, 16), 256, 0, stream>>>(qpk, KTpk, Vpk, Xpk);
  gemm_mfma<0><<<dim3(8, 8, 16), 256, 0, stream>>>(WpPk, Xpk, bp, out);
}

// Round 7
// 543.969 us; speedup vs baseline: 1.8188x; 1.2763x over previous
//
#include <hip/hip_runtime.h>
#include <cstdint>
#include <cstddef>

typedef unsigned short u16;
typedef __bf16 bf16x8 __attribute__((ext_vector_type(8)));
typedef float f32x4 __attribute__((ext_vector_type(4)));

typedef __attribute__((address_space(1))) const void global_cvoid;
typedef __attribute__((address_space(3))) void lds_void;

__device__ __forceinline__ void async16(void* lds, const void* g) {
  __builtin_amdgcn_global_load_lds((global_cvoid*)g, (lds_void*)lds, 16, 0, 0);
}

__device__ __forceinline__ u16 f2bf(float f) {  // RNE fp32 -> bf16 bits
  uint32_t u = __float_as_uint(f);
  return (u16)((u + 0x7fffu + ((u >> 16) & 1u)) >> 16);
}

// Pack 4 fp32 -> 12 u16 {h,l,h} stream (B-side pattern), written as 6 dwords.
__device__ __forceinline__ void pack4_hlh(uint32_t* dst, const float* v) {
  u16 h[4], l[4];
#pragma unroll
  for (int u = 0; u < 4; ++u) {
    h[u] = f2bf(v[u]);
    float hf = __uint_as_float((uint32_t)h[u] << 16);
    l[u] = f2bf(v[u] - hf);
  }
  dst[0] = (uint32_t)h[0] | ((uint32_t)l[0] << 16);
  dst[1] = (uint32_t)h[0] | ((uint32_t)h[1] << 16);
  dst[2] = (uint32_t)l[1] | ((uint32_t)h[1] << 16);
  dst[3] = (uint32_t)h[2] | ((uint32_t)l[2] << 16);
  dst[4] = (uint32_t)h[2] | ((uint32_t)h[3] << 16);
  dst[5] = (uint32_t)l[3] | ((uint32_t)h[3] << 16);
}

// Pack 4 fp32 -> 12 u16 {h,h,l} stream (A-side pattern), 6 dwords.
// Complementary to {h,l,h}: products give h*h + h*l + l*h per value.
__device__ __forceinline__ void pack4_hhl(uint32_t* dst, const float* v) {
  u16 h[4], l[4];
#pragma unroll
  for (int u = 0; u < 4; ++u) {
    h[u] = f2bf(v[u]);
    float hf = __uint_as_float((uint32_t)h[u] << 16);
    l[u] = f2bf(v[u] - hf);
  }
  dst[0] = (uint32_t)h[0] | ((uint32_t)h[0] << 16);
  dst[1] = (uint32_t)l[0] | ((uint32_t)h[1] << 16);
  dst[2] = (uint32_t)h[1] | ((uint32_t)l[1] << 16);
  dst[3] = (uint32_t)h[2] | ((uint32_t)h[2] << 16);
  dst[4] = (uint32_t)l[2] | ((uint32_t)h[3] << 16);
  dst[5] = (uint32_t)h[3] | ((uint32_t)l[3] << 16);
}

// ---------------------------------------------------------------------------
// Pack W (A operand): out[d][3c+{0,1,2}] = {hi, hi, lo} of W[d][c].
// ---------------------------------------------------------------------------
__global__ __launch_bounds__(256) void pack_w(const float* __restrict__ W,
                                              u16* __restrict__ out) {
  int idx = blockIdx.x * 256 + threadIdx.x;
  int d = idx >> 10, c = idx & 1023;
  float f = W[idx];
  u16 h = f2bf(f);
  float hf = __uint_as_float((uint32_t)h << 16);
  u16 l = f2bf(f - hf);
  u16* dst = out + (size_t)d * 3072 + 3 * c;
  dst[0] = h; dst[1] = h; dst[2] = l;
}

// ---------------------------------------------------------------------------
// Pack+transpose X (B operand): out[b][n][3c+{0,1,2}] = {h,l,h} of X[b][c][n].
// (still used for the Vx input pack)
// ---------------------------------------------------------------------------
__global__ __launch_bounds__(256) void pack_x(const float* __restrict__ X,
                                              u16* __restrict__ out) {
  const int b = blockIdx.z, c0 = blockIdx.y * 32, n0 = blockIdx.x * 32;
  __shared__ float tile[32][33];
  const float* src = X + ((size_t)b * 1024 + c0) * 1024 + n0;
  const int tc = threadIdx.x >> 5, tn = threadIdx.x & 31;
#pragma unroll
  for (int i = 0; i < 4; ++i)
    tile[tc + i * 8][tn] = src[(size_t)(tc + i * 8) * 1024 + tn];
  __syncthreads();
  const int nl = threadIdx.x >> 3, cg = (threadIdx.x & 7) * 4;
  float v[4];
#pragma unroll
  for (int u = 0; u < 4; ++u) v[u] = tile[cg + u][nl];
  uint32_t* dst = (uint32_t*)(out + ((size_t)b * 1024 + n0 + nl) * 3072 +
                              (size_t)(c0 + cg) * 3);
  pack4_hlh(dst, v);
}

// ---------------------------------------------------------------------------
// Pack+transpose Tx: Tx[b][1024 c][77 t] -> TxPk[b][128 t][3072] {h,l,h},
// rows t>=77 zeroed. grid (4 t-tiles, 32 c-tiles, 16 b).
// ---------------------------------------------------------------------------
__global__ __launch_bounds__(256) void pack_tx(const float* __restrict__ Tx,
                                               u16* __restrict__ out) {
  const int b = blockIdx.z, c0 = blockIdx.y * 32, t0 = blockIdx.x * 32;
  __shared__ float tile[32][33];
  const float* src = Tx + ((size_t)b * 1024 + c0) * 77;
  const int tc = threadIdx.x >> 5, tn = threadIdx.x & 31;
#pragma unroll
  for (int i = 0; i < 4; ++i) {
    int t = t0 + tn;
    tile[tc + i * 8][tn] = (t < 77) ? src[(size_t)(tc + i * 8) * 77 + t] : 0.f;
  }
  __syncthreads();
  const int nl = threadIdx.x >> 3, cg = (threadIdx.x & 7) * 4;
  float v[4];
#pragma unroll
  for (int u = 0; u < 4; ++u) v[u] = tile[cg + u][nl];
  uint32_t* dst = (uint32_t*)(out + ((size_t)b * 128 + t0 + nl) * 3072 +
                              (size_t)(c0 + cg) * 3);
  pack4_hlh(dst, v);
}

// ---------------------------------------------------------------------------
// K repack for attention: kvbuf K rows [b][h*256+d][80 t] (fp32) ->
// KTpk[(b*8+h)][t][384] = {h,h,l} over d (transposed, d-contiguous).
// grid (8 h, 16 b), 256 threads.
// ---------------------------------------------------------------------------
__global__ __launch_bounds__(256) void pack_kt(const float* __restrict__ kv,
                                               u16* __restrict__ out) {
  const int h = blockIdx.x, b = blockIdx.y;
  __shared__ float sk[128][81];
  const float* src = kv + ((size_t)b * 2048 + h * 256) * 80;
#pragma unroll
  for (int it = 0; it < 40; ++it) {
    int idx = it * 256 + threadIdx.x;  // 0..10239 over [d][t]
    sk[idx / 80][idx % 80] = src[idx];
  }
  __syncthreads();
#pragma unroll
  for (int it = 0; it < 10; ++it) {
    int idx = it * 256 + threadIdx.x;  // 0..2559 over (t, d-group)
    int t = idx >> 5, dg = (idx & 31) * 4;
    float v[4];
#pragma unroll
    for (int u = 0; u < 4; ++u) v[u] = sk[dg + u][t];
    uint32_t* dst = (uint32_t*)(out + ((size_t)(b * 8 + h) * 80 + t) * 384 +
                                (size_t)3 * dg);
    pack4_hhl(dst, v);
  }
}

// ---------------------------------------------------------------------------
// V repack for attention: kvbuf V rows [b][h*256+128+d][80 t] (fp32) ->
// Vpk[(b*8+h)][d][256] = {h,l,h} over t (k' = 3*80 = 240, cols 240..256 = 0).
// grid (8 h, 16 b), 256 threads.
// ---------------------------------------------------------------------------
__global__ __launch_bounds__(256) void pack_v(const float* __restrict__ kv,
                                              u16* __restrict__ out) {
  const int h = blockIdx.x, b = blockIdx.y;
  const float* src = kv + ((size_t)b * 2048 + h * 256 + 128) * 80;
  u16* ob = out + (size_t)(b * 8 + h) * 128 * 256;
#pragma unroll
  for (int it = 0; it < 10; ++it) {
    int idx = it * 256 + threadIdx.x;  // 0..2559 over (d, t-group)
    int d = idx / 20, tg = idx % 20;
    float4 v4 = *(const float4*)(src + (size_t)d * 80 + tg * 4);
    float v[4] = {v4.x, v4.y, v4.z, v4.w};
    uint32_t* dst = (uint32_t*)(ob + (size_t)d * 256 + 12 * tg);
    pack4_hlh(dst, v);
  }
  // zero pad cols [240,256): 128 rows x 16 u16; 256 threads -> 1 store each
  {
    int row = threadIdx.x >> 1, part = threadIdx.x & 1;
    *(uint4*)(ob + (size_t)row * 256 + 240 + part * 8) = make_uint4(0, 0, 0, 0);
  }
}

// ---------------------------------------------------------------------------
// MFMA GEMM, 256x256 tile, deep-pipelined (T3+T4+T5 port of the 8-phase
// template onto our fragment-linear packed layout — no swizzle needed, the
// packed format IS the conflict-free LDS image).
//   512 threads = 8 waves (2 M x 4 N); per-wave output 128x64 = acc[8][4].
//   K tiles of 32 u16 (1 MFMA k-slice), 96 tiles. 4 LDS buffers x 32 KiB
//   (A 16 frags x 1KB + B 16 frags x 1KB) = 128 KiB, 1 block/CU.
//   Per tile, 2 phases:
//     phA: ds_read A[0..4)+B[0..4) -> barrier -> lgkm0 -> prio1 16 MFMA
//     phB: ds_read A[4..8) -> lgkm0 (drain BEFORE barrier => buffer free)
//          -> counted vmcnt (confirm tile t+1; never 0 until drain)
//          -> barrier -> stage tile t+4 into buf (t&3) [safe: all waves
//          drained pre-barrier] -> prio1 16 MFMA
//   vmcnt ledger (4 loads/wave/tile): steady vmcnt(8) = tiles t+2,t+3 in
//   flight; epilog 8->4->0 at t=93,94.
// K-accumulation order identical to the 2-phase version => bit-identical.
// OUTMODE 0: fp32 Y[b][d][n]+bias. OUTMODE 1: packed u16 qpk[b][n][3d].
// ---------------------------------------------------------------------------
template <int OUTMODE>
__global__ __launch_bounds__(512, 2) void gemm_mfma(
    const u16* __restrict__ Apk, const u16* __restrict__ Bpk,
    const float* __restrict__ bias, void* __restrict__ Yv)
{
  const int b  = blockIdx.z;
  const int d0 = blockIdx.y * 256;
  const int n0 = blockIdx.x * 256;
  const int tid  = threadIdx.x;
  const int lane = tid & 63;
  const int w    = tid >> 6;          // 0..7
  const int wm   = w >> 2, wn = w & 3;
  const int lr   = lane & 15;
  const int lkb  = (lane >> 4) * 16;  // byte chunk within a 64B row-step

  __shared__ __align__(16) char smem[131072];  // 4 bufs x (A 16K | B 16K)

  const u16* Bb = Bpk + (size_t)b * 1024 * 3072;

  // Staging ownership: wave w stages frags g = 4w..4w+3.
  // g < 16: A frag s=g (rows d0+16s..+16); else B frag s=g-16 (rows n0+16s..).
  const char* gsrc[4];
  int ldst[4];
#pragma unroll
  for (int f = 0; f < 4; ++f) {
    int g = w * 4 + f;
    if (g < 16) {
      gsrc[f] = (const char*)(Apk + (size_t)(d0 + g * 16 + lr) * 3072) + lkb;
      ldst[f] = g * 1024;
    } else {
      gsrc[f] = (const char*)(Bb + (size_t)(n0 + (g - 16) * 16 + lr) * 3072) + lkb;
      ldst[f] = 16384 + (g - 16) * 1024;
    }
  }

  auto stage = [&](int t) {
    char* base = smem + (t & 3) * 32768;
#pragma unroll
    for (int f = 0; f < 4; ++f)
      async16(base + ldst[f], gsrc[f] + (size_t)t * 64);
  };

  f32x4 acc[8][4];
#pragma unroll
  for (int i = 0; i < 8; ++i)
#pragma unroll
    for (int j = 0; j < 4; ++j) acc[i][j] = (f32x4){0.f, 0.f, 0.f, 0.f};

  stage(0); stage(1); stage(2); stage(3);
  asm volatile("s_waitcnt vmcnt(12)" ::: "memory");   // tile 0 resident
  __builtin_amdgcn_s_barrier();

  for (int t = 0; t < 96; ++t) {
    const char* bufA = smem + (size_t)(t & 3) * 32768 + (size_t)lane * 16;
    const char* bufB = bufA + 16384;

    // ---- phase A: A-half 0 x all B ----
    bf16x8 af[4], bfv[4];
#pragma unroll
    for (int i = 0; i < 4; ++i)
      af[i] = *(const bf16x8*)(bufA + (wm * 8 + i) * 1024);
#pragma unroll
    for (int j = 0; j < 4; ++j)
      bfv[j] = *(const bf16x8*)(bufB + (wn * 4 + j) * 1024);
    asm volatile("" ::: "memory");
    __builtin_amdgcn_s_barrier();
    asm volatile("s_waitcnt lgkmcnt(0)" ::: "memory");
    __builtin_amdgcn_sched_barrier(0);
    __builtin_amdgcn_s_setprio(1);
#pragma unroll
    for (int i = 0; i < 4; ++i)
#pragma unroll
      for (int j = 0; j < 4; ++j)
        acc[i][j] = __builtin_amdgcn_mfma_f32_16x16x32_bf16(af[i], bfv[j], acc[i][j], 0, 0, 0);
    __builtin_amdgcn_s_setprio(0);

    // ---- phase B: A-half 1 x all B ----
#pragma unroll
    for (int i = 0; i < 4; ++i)
      af[i] = *(const bf16x8*)(bufA + (wm * 8 + 4 + i) * 1024);
    asm volatile("s_waitcnt lgkmcnt(0)" ::: "memory");  // drain BEFORE barrier
    __builtin_amdgcn_sched_barrier(0);
    if (t < 93)       asm volatile("s_waitcnt vmcnt(8)" ::: "memory");
    else if (t == 93) asm volatile("s_waitcnt vmcnt(4)" ::: "memory");
    else if (t == 94) asm volatile("s_waitcnt vmcnt(0)" ::: "memory");
    __builtin_amdgcn_s_barrier();       // buf (t&3) now free for writes
    if (t + 4 < 96) stage(t + 4);
    __builtin_amdgcn_s_setprio(1);
#pragma unroll
    for (int i = 0; i < 4; ++i)
#pragma unroll
      for (int j = 0; j < 4; ++j)
        acc[4 + i][j] = __builtin_amdgcn_mfma_f32_16x16x32_bf16(af[i], bfv[j], acc[4 + i][j], 0, 0, 0);
    __builtin_amdgcn_s_setprio(0);
  }

#pragma unroll
  for (int i = 0; i < 8; ++i) {
    const int dbase = d0 + wm * 128 + i * 16 + (lane >> 4) * 4;
    const float4 bv = *(const float4*)(bias + dbase);
#pragma unroll
    for (int j = 0; j < 4; ++j) {
      const int n = n0 + wn * 64 + j * 16 + lr;
      if (OUTMODE == 0) {
        float* yp = (float*)Yv + ((size_t)b * 1024 + dbase) * 1024 + n;
        yp[0]        = acc[i][j].x + bv.x;
        yp[1024]     = acc[i][j].y + bv.y;
        yp[2 * 1024] = acc[i][j].z + bv.z;
        yp[3 * 1024] = acc[i][j].w + bv.w;
      } else {
        float v[4] = {acc[i][j].x + bv.x, acc[i][j].y + bv.y,
                      acc[i][j].z + bv.z, acc[i][j].w + bv.w};
        uint32_t* dst = (uint32_t*)((u16*)Yv +
                                    ((size_t)b * 1024 + n) * 3072 + 3 * dbase);
        pack4_hlh(dst, v);
      }
    }
  }
}

// ---------------------------------------------------------------------------
// KV MFMA GEMM (round-6 counted-vmcnt 2-deep structure, unchanged):
// kv[b][e][t(80pad)] = sum Wkv[e][c] Tx[b][c][t] + bkv[e]
// ---------------------------------------------------------------------------
__global__ __launch_bounds__(256) void gemm_kv_mfma(
    const u16* __restrict__ Apk, const u16* __restrict__ Bpk,
    const float* __restrict__ bias, float* __restrict__ Y)
{
  const int b  = blockIdx.y;
  const int d0 = blockIdx.x * 128;
  const int tid  = threadIdx.x;
  const int lane = tid & 63;
  const int w    = tid >> 6;
  const int wm   = w >> 1, wn = w & 1;

  __shared__ __align__(16) char smem[65536];

  const int lr = lane & 15;
  const int lk = (lane >> 4) * 8;

  const u16* Bb = Bpk + (size_t)b * 128 * 3072;
  const char* gA0 = (const char*)(Apk + ((size_t)(d0 + (w * 2 + 0) * 16 + lr) * 3072 + lk));
  const char* gA1 = (const char*)(Apk + ((size_t)(d0 + (w * 2 + 1) * 16 + lr) * 3072 + lk));
  const char* gB0 = (const char*)(Bb  + ((size_t)((w * 2 + 0) * 16 + lr) * 3072 + lk));
  const char* gB1 = (const char*)(Bb  + ((size_t)((w * 2 + 1) * 16 + lr) * 3072 + lk));

  auto stage = [&](int p, int ks) {
    char* ba = smem + p * 32768 + (w * 2) * 1024;
    char* bb = ba + 16384;
    const int kb = ks * 128;
#pragma unroll
    for (int k2 = 0; k2 < 2; ++k2) {
      async16(ba + k2 * 8192,        gA0 + kb + k2 * 64);
      async16(ba + k2 * 8192 + 1024, gA1 + kb + k2 * 64);
      async16(bb + k2 * 8192,        gB0 + kb + k2 * 64);
      async16(bb + k2 * 8192 + 1024, gB1 + kb + k2 * 64);
    }
  };

  f32x4 acc[4][4];
#pragma unroll
  for (int i = 0; i < 4; ++i)
#pragma unroll
    for (int j = 0; j < 4; ++j) acc[i][j] = (f32x4){0.f, 0.f, 0.f, 0.f};

  stage(0, 0);
  stage(1, 1);

  for (int ks = 0; ks < 48; ++ks) {
    if (ks < 47) asm volatile("s_waitcnt vmcnt(8)" ::: "memory");
    else         asm volatile("s_waitcnt vmcnt(0)" ::: "memory");
    __builtin_amdgcn_s_barrier();

    const int p = ks & 1;
    const char* baseA = smem + p * 32768 + wm * 4096 + lane * 16;
    const char* baseB = smem + p * 32768 + 16384 + wn * 4096 + lane * 16;
#pragma unroll
    for (int k2 = 0; k2 < 2; ++k2) {
      bf16x8 af[4], bfv[4];
#pragma unroll
      for (int i = 0; i < 4; ++i) {
        af[i]  = *(const bf16x8*)(baseA + k2 * 8192 + i * 1024);
        bfv[i] = *(const bf16x8*)(baseB + k2 * 8192 + i * 1024);
      }
#pragma unroll
      for (int i = 0; i < 4; ++i)
#pragma unroll
        for (int j = 0; j < 4; ++j)
          acc[i][j] = __builtin_amdgcn_mfma_f32_16x16x32_bf16(af[i], bfv[j], acc[i][j], 0, 0, 0);
    }

    asm volatile("" ::: "memory");
    __builtin_amdgcn_s_barrier();
    if (ks + 2 < 48) stage(p, ks + 2);
  }

#pragma unroll
  for (int i = 0; i < 4; ++i) {
    const int dbase = d0 + wm * 64 + i * 16 + (lane >> 4) * 4;
    const float4 bv = *(const float4*)(bias + dbase);
#pragma unroll
    for (int j = 0; j < 4; ++j) {
      const int n = wn * 64 + j * 16 + lr;
      if (n < 80) {
        float* yp = Y + ((size_t)b * 2048 + dbase) * 80 + n;
        yp[0]      = acc[i][j].x + bv.x;
        yp[80]     = acc[i][j].y + bv.y;
        yp[160]    = acc[i][j].z + bv.z;
        yp[240]    = acc[i][j].w + bv.w;
      }
    }
  }
}

// ---------------------------------------------------------------------------
// MFMA attention, fused output pack (unchanged from round 5/6).
// ---------------------------------------------------------------------------
__global__ __launch_bounds__(256, 2) void attn_mfma(
    const u16* __restrict__ qpk,   // [B][1024 n][3072] {h,l,h}
    const u16* __restrict__ ktpk,  // [B*8][80 t][384]  {h,h,l}
    const u16* __restrict__ vpk,   // [B*8][128 d][256] {h,l,h}, 240..256 = 0
    u16* __restrict__ xout)        // [B][1024 n][3072] {h,l,h} packed
{
  const int b  = blockIdx.z;
  const int h  = blockIdx.y;
  const int n0 = blockIdx.x * 128;
  const int tid  = threadIdx.x;
  const int w    = tid >> 6;
  const int lane = tid & 63;
  const int lr = lane & 15;      // frag row / output col
  const int lc = lane >> 4;      // frag k-chunk / output row group
  const float scale = 0.08838834764831845f;  // 128^-0.5

  __shared__ u16 Plds[4][32 * 256];   // 64 KiB total, wave-private slices
  u16* Pw = &Plds[w][0];

  // zero P pad cols [240,256) for this wave's 32 rows (1 x 16B store/lane)
  {
    int row = lane & 31, part = lane >> 5;
    *(uint4*)&Pw[row * 256 + 240 + part * 8] = make_uint4(0, 0, 0, 0);
  }

  // ---------------- QK^T ----------------
  const u16* qb = qpk + ((size_t)b * 1024 + n0 + w * 32 + lr) * 3072 +
                  384 * h + lc * 8;
  const u16* kb = ktpk + (size_t)(b * 8 + h) * 80 * 384 + (size_t)lr * 384 + lc * 8;

  f32x4 accs[2][5];
#pragma unroll
  for (int ni = 0; ni < 2; ++ni)
#pragma unroll
    for (int tt = 0; tt < 5; ++tt) accs[ni][tt] = (f32x4){0.f, 0.f, 0.f, 0.f};

  for (int ks = 0; ks < 12; ++ks) {
    bf16x8 qa[2], kt[5];
    qa[0] = *(const bf16x8*)(qb + ks * 32);
    qa[1] = *(const bf16x8*)(qb + 16 * 3072 + ks * 32);
#pragma unroll
    for (int tt = 0; tt < 5; ++tt)
      kt[tt] = *(const bf16x8*)(kb + (size_t)tt * 16 * 384 + ks * 32);
#pragma unroll
    for (int ni = 0; ni < 2; ++ni)
#pragma unroll
      for (int tt = 0; tt < 5; ++tt)
        accs[ni][tt] = __builtin_amdgcn_mfma_f32_16x16x32_bf16(qa[ni], kt[tt], accs[ni][tt], 0, 0, 0);
  }

  // mask t >= 77 (t = tt*16 + lr; only tt==4, lr>=13 invalid)
  if (lr >= 13) {
    accs[0][4] = (f32x4){-3.0e38f, -3.0e38f, -3.0e38f, -3.0e38f};
    accs[1][4] = (f32x4){-3.0e38f, -3.0e38f, -3.0e38f, -3.0e38f};
  }

  // ---------------- softmax + P pack to LDS ----------------
#pragma unroll
  for (int ni = 0; ni < 2; ++ni) {
    f32x4 mx = accs[ni][0];
#pragma unroll
    for (int tt = 1; tt < 5; ++tt) {
      mx.x = fmaxf(mx.x, accs[ni][tt].x);
      mx.y = fmaxf(mx.y, accs[ni][tt].y);
      mx.z = fmaxf(mx.z, accs[ni][tt].z);
      mx.w = fmaxf(mx.w, accs[ni][tt].w);
    }
#pragma unroll
    for (int mk = 1; mk <= 8; mk <<= 1) {
      mx.x = fmaxf(mx.x, __shfl_xor(mx.x, mk));
      mx.y = fmaxf(mx.y, __shfl_xor(mx.y, mk));
      mx.z = fmaxf(mx.z, __shfl_xor(mx.z, mk));
      mx.w = fmaxf(mx.w, __shfl_xor(mx.w, mk));
    }
    f32x4 sm = (f32x4){0.f, 0.f, 0.f, 0.f};
#pragma unroll
    for (int tt = 0; tt < 5; ++tt) {
      f32x4 e;
      e.x = __expf((accs[ni][tt].x - mx.x) * scale);
      e.y = __expf((accs[ni][tt].y - mx.y) * scale);
      e.z = __expf((accs[ni][tt].z - mx.z) * scale);
      e.w = __expf((accs[ni][tt].w - mx.w) * scale);
      accs[ni][tt] = e;
      sm += e;
    }
#pragma unroll
    for (int mk = 1; mk <= 8; mk <<= 1) {
      sm.x += __shfl_xor(sm.x, mk);
      sm.y += __shfl_xor(sm.y, mk);
      sm.z += __shfl_xor(sm.z, mk);
      sm.w += __shfl_xor(sm.w, mk);
    }
    f32x4 inv = (f32x4){1.f / sm.x, 1.f / sm.y, 1.f / sm.z, 1.f / sm.w};
    // write P {h,h,l} at [row][3t..3t+2]; row = ni*16 + lc*4 + comp, t = tt*16+lr
#pragma unroll
    for (int tt = 0; tt < 5; ++tt) {
#pragma unroll
      for (int c = 0; c < 4; ++c) {
        float pv = accs[ni][tt][c] * inv[c];
        int row = ni * 16 + lc * 4 + c;
        int t = tt * 16 + lr;
        u16 hh = f2bf(pv);
        float hf = __uint_as_float((uint32_t)hh << 16);
        u16 ll = f2bf(pv - hf);
        u16* pp = &Pw[row * 256 + 3 * t];
        pp[0] = hh; pp[1] = hh; pp[2] = ll;
      }
    }
  }

  // ---------------- PV ----------------
  f32x4 acco[2][8];
#pragma unroll
  for (int ni = 0; ni < 2; ++ni)
#pragma unroll
    for (int dj = 0; dj < 8; ++dj) acco[ni][dj] = (f32x4){0.f, 0.f, 0.f, 0.f};

  const u16* vb = vpk + (size_t)(b * 8 + h) * 128 * 256 + (size_t)lr * 256 + lc * 8;
  const u16* pb = &Pw[lr * 256 + lc * 8];

  for (int ks = 0; ks < 8; ++ks) {
    bf16x8 pa[2], vv[8];
    pa[0] = *(const bf16x8*)(pb + ks * 32);
    pa[1] = *(const bf16x8*)(pb + 16 * 256 + ks * 32);
#pragma unroll
    for (int dj = 0; dj < 8; ++dj)
      vv[dj] = *(const bf16x8*)(vb + (size_t)dj * 16 * 256 + ks * 32);
#pragma unroll
    for (int ni = 0; ni < 2; ++ni)
#pragma unroll
      for (int dj = 0; dj < 8; ++dj)
        acco[ni][dj] = __builtin_amdgcn_mfma_f32_16x16x32_bf16(pa[ni], vv[dj], acco[ni][dj], 0, 0, 0);
  }

  // ---------------- fused epilogue: pack to Xpk[b][n][3c] ----------------
  float* Pf = (float*)Pw;
#pragma unroll
  for (int ni = 0; ni < 2; ++ni)
#pragma unroll
    for (int dj = 0; dj < 8; ++dj) {
      const int dl = dj * 16 + lr;
#pragma unroll
      for (int c = 0; c < 4; ++c)
        Pf[(ni * 16 + lc * 4 + c) * 128 + dl] = acco[ni][dj][c];
    }

  const int prow = lane >> 5;   // 0..1
  const int pgrp = lane & 31;   // 0..31 (d-group of 4)
#pragma unroll
  for (int r2 = 0; r2 < 16; ++r2) {
    const int row = r2 * 2 + prow;
    f32x4 vv4 = *(const f32x4*)&Pf[row * 128 + pgrp * 4];
    float v[4] = {vv4.x, vv4.y, vv4.z, vv4.w};
    uint32_t* dst = (uint32_t*)(xout +
        ((size_t)b * 1024 + n0 + w * 32 + row) * 3072 + 384 * h + 12 * pgrp);
    pack4_hlh(dst, v);
  }
}

// ---------------------------------------------------------------------------
extern "C" void kernel_launch(void* const* d_in, const int* in_sizes, int n_in,
                              void* d_out, int out_size, void* d_ws, size_t ws_size,
                              hipStream_t stream) {
  const float* Vx  = (const float*)d_in[0];
  const float* Tx  = (const float*)d_in[1];
  const float* Wq  = (const float*)d_in[2];
  const float* bq  = (const float*)d_in[3];
  const float* Wkv = (const float*)d_in[4];
  const float* bkv = (const float*)d_in[5];
  const float* Wp  = (const float*)d_in[6];
  const float* bp  = (const float*)d_in[7];
  float* out = (float*)d_out;

  char* ws = (char*)d_ws;
  const size_t MiB = (size_t)1 << 20;
  // Lifetime-aliased layout (total 239 MiB). Step order:
  //  1 packs (W/Vx/Tx)   2 gemm#1 -> qpk (fused pack)   3 gemm kv
  //  4 pack_kt/pack_v    5 attn -> Xpk (fused pack)     6 gemm#2 -> out
  u16*   Xpk      = (u16*)(ws + 0);
  u16*   qpk      = (u16*)(ws + 96 * MiB);
  u16*   WqPk     = (u16*)(ws + 192 * MiB);
  u16*   KTpk     = (u16*)(ws + 192 * MiB);
  u16*   WkvPk    = (u16*)(ws + 198 * MiB);
  u16*   Vpk      = (u16*)(ws + 200 * MiB);
  u16*   TxPk     = (u16*)(ws + 210 * MiB);
  float* kvbuf    = (float*)(ws + 222 * MiB);
  u16*   WpPk     = (u16*)(ws + 233 * MiB);

  pack_w<<<4096, 256, 0, stream>>>(Wq, WqPk);
  pack_w<<<4096, 256, 0, stream>>>(Wp, WpPk);
  pack_w<<<8192, 256, 0, stream>>>(Wkv, WkvPk);
  pack_x<<<dim3(32, 32, 16), 256, 0, stream>>>(Vx, Xpk);
  pack_tx<<<dim3(4, 32, 16), 256, 0, stream>>>(Tx, TxPk);
  gemm_mfma<1><<<dim3(4, 4, 16), 512, 0, stream>>>(WqPk, Xpk, bq, qpk);
  gemm_kv_mfma<<<dim3(16, 16), 256, 0, stream>>>(WkvPk, TxPk, bkv, kvbuf);
  pack_kt<<<dim3(8, 16), 256, 0, stream>>>(kvbuf, KTpk);
  pack_v<<<dim3(8, 16), 256, 0, stream>>>(kvbuf, Vpk);
  attn_mfma<<<dim3(8, 8, 16), 256, 0, stream>>>(qpk, KTpk, Vpk, Xpk);
  gemm_mfma<0><<<dim3(4, 4, 16), 512, 0, stream>>>(WpPk, Xpk, bp, out);
}

// Round 8
// 530.650 us; speedup vs baseline: 1.8644x; 1.0251x over previous
//
#include <hip/hip_runtime.h>
#include <cstdint>
#include <cstddef>

typedef unsigned short u16;
typedef __bf16 bf16x8 __attribute__((ext_vector_type(8)));
typedef float f32x4 __attribute__((ext_vector_type(4)));

typedef __attribute__((address_space(1))) const void global_cvoid;
typedef __attribute__((address_space(3))) void lds_void;

__device__ __forceinline__ void async16(void* lds, const void* g) {
  __builtin_amdgcn_global_load_lds((global_cvoid*)g, (lds_void*)lds, 16, 0, 0);
}

__device__ __forceinline__ u16 f2bf(float f) {  // RNE fp32 -> bf16 bits
  uint32_t u = __float_as_uint(f);
  return (u16)((u + 0x7fffu + ((u >> 16) & 1u)) >> 16);
}

// Pack 4 fp32 -> 12 u16 {h,l,h} stream (B-side pattern), written as 6 dwords.
__device__ __forceinline__ void pack4_hlh(uint32_t* dst, const float* v) {
  u16 h[4], l[4];
#pragma unroll
  for (int u = 0; u < 4; ++u) {
    h[u] = f2bf(v[u]);
    float hf = __uint_as_float((uint32_t)h[u] << 16);
    l[u] = f2bf(v[u] - hf);
  }
  dst[0] = (uint32_t)h[0] | ((uint32_t)l[0] << 16);
  dst[1] = (uint32_t)h[0] | ((uint32_t)h[1] << 16);
  dst[2] = (uint32_t)l[1] | ((uint32_t)h[1] << 16);
  dst[3] = (uint32_t)h[2] | ((uint32_t)l[2] << 16);
  dst[4] = (uint32_t)h[2] | ((uint32_t)h[3] << 16);
  dst[5] = (uint32_t)l[3] | ((uint32_t)h[3] << 16);
}

// Pack 4 fp32 -> 12 u16 {h,h,l} stream (A-side pattern), 6 dwords.
// Complementary to {h,l,h}: products give h*h + h*l + l*h per value.
__device__ __forceinline__ void pack4_hhl(uint32_t* dst, const float* v) {
  u16 h[4], l[4];
#pragma unroll
  for (int u = 0; u < 4; ++u) {
    h[u] = f2bf(v[u]);
    float hf = __uint_as_float((uint32_t)h[u] << 16);
    l[u] = f2bf(v[u] - hf);
  }
  dst[0] = (uint32_t)h[0] | ((uint32_t)h[0] << 16);
  dst[1] = (uint32_t)l[0] | ((uint32_t)h[1] << 16);
  dst[2] = (uint32_t)h[1] | ((uint32_t)l[1] << 16);
  dst[3] = (uint32_t)h[2] | ((uint32_t)h[2] << 16);
  dst[4] = (uint32_t)l[2] | ((uint32_t)h[3] << 16);
  dst[5] = (uint32_t)h[3] | ((uint32_t)l[3] << 16);
}

// ---------------------------------------------------------------------------
// Pack W (A operand): out[d][3c+{0,1,2}] = {hi, hi, lo} of W[d][c].
// ---------------------------------------------------------------------------
__global__ __launch_bounds__(256) void pack_w(const float* __restrict__ W,
                                              u16* __restrict__ out) {
  int idx = blockIdx.x * 256 + threadIdx.x;
  int d = idx >> 10, c = idx & 1023;
  float f = W[idx];
  u16 h = f2bf(f);
  float hf = __uint_as_float((uint32_t)h << 16);
  u16 l = f2bf(f - hf);
  u16* dst = out + (size_t)d * 3072 + 3 * c;
  dst[0] = h; dst[1] = h; dst[2] = l;
}

// ---------------------------------------------------------------------------
// Pack+transpose X (B operand): out[b][n][3c+{0,1,2}] = {h,l,h} of X[b][c][n].
// (still used for the Vx input pack)
// ---------------------------------------------------------------------------
__global__ __launch_bounds__(256) void pack_x(const float* __restrict__ X,
                                              u16* __restrict__ out) {
  const int b = blockIdx.z, c0 = blockIdx.y * 32, n0 = blockIdx.x * 32;
  __shared__ float tile[32][33];
  const float* src = X + ((size_t)b * 1024 + c0) * 1024 + n0;
  const int tc = threadIdx.x >> 5, tn = threadIdx.x & 31;
#pragma unroll
  for (int i = 0; i < 4; ++i)
    tile[tc + i * 8][tn] = src[(size_t)(tc + i * 8) * 1024 + tn];
  __syncthreads();
  const int nl = threadIdx.x >> 3, cg = (threadIdx.x & 7) * 4;
  float v[4];
#pragma unroll
  for (int u = 0; u < 4; ++u) v[u] = tile[cg + u][nl];
  uint32_t* dst = (uint32_t*)(out + ((size_t)b * 1024 + n0 + nl) * 3072 +
                              (size_t)(c0 + cg) * 3);
  pack4_hlh(dst, v);
}

// ---------------------------------------------------------------------------
// Pack+transpose Tx: Tx[b][1024 c][77 t] -> TxPk[b][128 t][3072] {h,l,h},
// rows t>=77 zeroed. grid (4 t-tiles, 32 c-tiles, 16 b).
// ---------------------------------------------------------------------------
__global__ __launch_bounds__(256) void pack_tx(const float* __restrict__ Tx,
                                               u16* __restrict__ out) {
  const int b = blockIdx.z, c0 = blockIdx.y * 32, t0 = blockIdx.x * 32;
  __shared__ float tile[32][33];
  const float* src = Tx + ((size_t)b * 1024 + c0) * 77;
  const int tc = threadIdx.x >> 5, tn = threadIdx.x & 31;
#pragma unroll
  for (int i = 0; i < 4; ++i) {
    int t = t0 + tn;
    tile[tc + i * 8][tn] = (t < 77) ? src[(size_t)(tc + i * 8) * 77 + t] : 0.f;
  }
  __syncthreads();
  const int nl = threadIdx.x >> 3, cg = (threadIdx.x & 7) * 4;
  float v[4];
#pragma unroll
  for (int u = 0; u < 4; ++u) v[u] = tile[cg + u][nl];
  uint32_t* dst = (uint32_t*)(out + ((size_t)b * 128 + t0 + nl) * 3072 +
                              (size_t)(c0 + cg) * 3);
  pack4_hlh(dst, v);
}

// ---------------------------------------------------------------------------
// K repack for attention: kvbuf K rows [b][h*256+d][80 t] (fp32) ->
// KTpk[(b*8+h)][t][384] = {h,h,l} over d (transposed, d-contiguous).
// grid (8 h, 16 b), 256 threads.
// ---------------------------------------------------------------------------
__global__ __launch_bounds__(256) void pack_kt(const float* __restrict__ kv,
                                               u16* __restrict__ out) {
  const int h = blockIdx.x, b = blockIdx.y;
  __shared__ float sk[128][81];
  const float* src = kv + ((size_t)b * 2048 + h * 256) * 80;
#pragma unroll
  for (int it = 0; it < 40; ++it) {
    int idx = it * 256 + threadIdx.x;  // 0..10239 over [d][t]
    sk[idx / 80][idx % 80] = src[idx];
  }
  __syncthreads();
#pragma unroll
  for (int it = 0; it < 10; ++it) {
    int idx = it * 256 + threadIdx.x;  // 0..2559 over (t, d-group)
    int t = idx >> 5, dg = (idx & 31) * 4;
    float v[4];
#pragma unroll
    for (int u = 0; u < 4; ++u) v[u] = sk[dg + u][t];
    uint32_t* dst = (uint32_t*)(out + ((size_t)(b * 8 + h) * 80 + t) * 384 +
                                (size_t)3 * dg);
    pack4_hhl(dst, v);
  }
}

// ---------------------------------------------------------------------------
// V repack for attention: kvbuf V rows [b][h*256+128+d][80 t] (fp32) ->
// Vpk[(b*8+h)][d][256] = {h,l,h} over t (k' = 3*80 = 240, cols 240..256 = 0).
// grid (8 h, 16 b), 256 threads.
// ---------------------------------------------------------------------------
__global__ __launch_bounds__(256) void pack_v(const float* __restrict__ kv,
                                              u16* __restrict__ out) {
  const int h = blockIdx.x, b = blockIdx.y;
  const float* src = kv + ((size_t)b * 2048 + h * 256 + 128) * 80;
  u16* ob = out + (size_t)(b * 8 + h) * 128 * 256;
#pragma unroll
  for (int it = 0; it < 10; ++it) {
    int idx = it * 256 + threadIdx.x;  // 0..2559 over (d, t-group)
    int d = idx / 20, tg = idx % 20;
    float4 v4 = *(const float4*)(src + (size_t)d * 80 + tg * 4);
    float v[4] = {v4.x, v4.y, v4.z, v4.w};
    uint32_t* dst = (uint32_t*)(ob + (size_t)d * 256 + 12 * tg);
    pack4_hlh(dst, v);
  }
  // zero pad cols [240,256): 128 rows x 16 u16; 256 threads -> 1 store each
  {
    int row = threadIdx.x >> 1, part = threadIdx.x & 1;
    *(uint4*)(ob + (size_t)row * 256 + 240 + part * 8) = make_uint4(0, 0, 0, 0);
  }
}

// ---------------------------------------------------------------------------
// MFMA GEMM, 256x256 tile, deep-pipelined, ONE barrier per K-tile.
// Dependency audit (why one barrier suffices):
//   - buf-t residency for the reads at the TOP of iter t is guaranteed by
//     iter t-1's vmcnt(8) (leaves tiles t+2,t+3 outstanding => t+1 retired)
//     followed by its barrier (all waves).
//   - buffer reuse: stage(t+4) writes buf t&3; every wave drained ALL its
//     ds_reads of buf t (lgkmcnt(0)) BEFORE the barrier that precedes the
//     stage => no wave can still be reading it.
// Per tile: reads(A-half0,B) -> MFMA x16 -> reads(A-half1) -> lgkm0 ->
//           vmcnt(8) -> barrier -> stage(t+4) -> MFMA x16.
// phA MFMA waits are compiler-inserted per-use lgkmcnt (no forced drain).
// K-accumulation order identical to round 7 => bit-identical output.
// OUTMODE 0: fp32 Y[b][d][n]+bias. OUTMODE 1: packed u16 qpk[b][n][3d].
// ---------------------------------------------------------------------------
template <int OUTMODE>
__global__ __launch_bounds__(512, 2) void gemm_mfma(
    const u16* __restrict__ Apk, const u16* __restrict__ Bpk,
    const float* __restrict__ bias, void* __restrict__ Yv)
{
  const int b  = blockIdx.z;
  const int d0 = blockIdx.y * 256;
  const int n0 = blockIdx.x * 256;
  const int tid  = threadIdx.x;
  const int lane = tid & 63;
  const int w    = tid >> 6;          // 0..7
  const int wm   = w >> 2, wn = w & 3;
  const int lr   = lane & 15;
  const int lkb  = (lane >> 4) * 16;  // byte chunk within a 64B row-step

  __shared__ __align__(16) char smem[131072];  // 4 bufs x (A 16K | B 16K)

  const u16* Bb = Bpk + (size_t)b * 1024 * 3072;

  // Staging ownership: wave w stages frags g = 4w..4w+3.
  // g < 16: A frag s=g (rows d0+16s..+16); else B frag s=g-16 (rows n0+16s..).
  const char* gsrc[4];
  int ldst[4];
#pragma unroll
  for (int f = 0; f < 4; ++f) {
    int g = w * 4 + f;
    if (g < 16) {
      gsrc[f] = (const char*)(Apk + (size_t)(d0 + g * 16 + lr) * 3072) + lkb;
      ldst[f] = g * 1024;
    } else {
      gsrc[f] = (const char*)(Bb + (size_t)(n0 + (g - 16) * 16 + lr) * 3072) + lkb;
      ldst[f] = 16384 + (g - 16) * 1024;
    }
  }

  auto stage = [&](int t) {
    char* base = smem + (t & 3) * 32768;
#pragma unroll
    for (int f = 0; f < 4; ++f)
      async16(base + ldst[f], gsrc[f] + (size_t)t * 64);
  };

  f32x4 acc[8][4];
#pragma unroll
  for (int i = 0; i < 8; ++i)
#pragma unroll
    for (int j = 0; j < 4; ++j) acc[i][j] = (f32x4){0.f, 0.f, 0.f, 0.f};

  stage(0); stage(1); stage(2); stage(3);
  asm volatile("s_waitcnt vmcnt(12)" ::: "memory");   // tile 0 resident
  __builtin_amdgcn_s_barrier();

  for (int t = 0; t < 96; ++t) {
    const char* bufA = smem + (size_t)(t & 3) * 32768 + (size_t)lane * 16;
    const char* bufB = bufA + 16384;

    // ---- phase A: A-half 0 x all B (compiler-scheduled lgkm waits) ----
    bf16x8 af[4], bfv[4], af2[4];
#pragma unroll
    for (int i = 0; i < 4; ++i)
      af[i] = *(const bf16x8*)(bufA + (wm * 8 + i) * 1024);
#pragma unroll
    for (int j = 0; j < 4; ++j)
      bfv[j] = *(const bf16x8*)(bufB + (wn * 4 + j) * 1024);
    __builtin_amdgcn_s_setprio(1);
#pragma unroll
    for (int i = 0; i < 4; ++i)
#pragma unroll
      for (int j = 0; j < 4; ++j)
        acc[i][j] = __builtin_amdgcn_mfma_f32_16x16x32_bf16(af[i], bfv[j], acc[i][j], 0, 0, 0);
    __builtin_amdgcn_s_setprio(0);

    // ---- phase B: A-half 1 x all B ----
#pragma unroll
    for (int i = 0; i < 4; ++i)
      af2[i] = *(const bf16x8*)(bufA + (wm * 8 + 4 + i) * 1024);
    asm volatile("s_waitcnt lgkmcnt(0)" ::: "memory");  // drain BEFORE barrier
    __builtin_amdgcn_sched_barrier(0);
    if (t < 93)       asm volatile("s_waitcnt vmcnt(8)" ::: "memory");
    else if (t == 93) asm volatile("s_waitcnt vmcnt(4)" ::: "memory");
    else              asm volatile("s_waitcnt vmcnt(0)" ::: "memory");
    __builtin_amdgcn_s_barrier();       // buf (t&3) now free; tile t+1 ready
    asm volatile("" ::: "memory");
    if (t + 4 < 96) stage(t + 4);
    __builtin_amdgcn_s_setprio(1);
#pragma unroll
    for (int i = 0; i < 4; ++i)
#pragma unroll
      for (int j = 0; j < 4; ++j)
        acc[4 + i][j] = __builtin_amdgcn_mfma_f32_16x16x32_bf16(af2[i], bfv[j], acc[4 + i][j], 0, 0, 0);
    __builtin_amdgcn_s_setprio(0);
  }

#pragma unroll
  for (int i = 0; i < 8; ++i) {
    const int dbase = d0 + wm * 128 + i * 16 + (lane >> 4) * 4;
    const float4 bv = *(const float4*)(bias + dbase);
#pragma unroll
    for (int j = 0; j < 4; ++j) {
      const int n = n0 + wn * 64 + j * 16 + lr;
      if (OUTMODE == 0) {
        float* yp = (float*)Yv + ((size_t)b * 1024 + dbase) * 1024 + n;
        yp[0]        = acc[i][j].x + bv.x;
        yp[1024]     = acc[i][j].y + bv.y;
        yp[2 * 1024] = acc[i][j].z + bv.z;
        yp[3 * 1024] = acc[i][j].w + bv.w;
      } else {
        float v[4] = {acc[i][j].x + bv.x, acc[i][j].y + bv.y,
                      acc[i][j].z + bv.z, acc[i][j].w + bv.w};
        uint32_t* dst = (uint32_t*)((u16*)Yv +
                                    ((size_t)b * 1024 + n) * 3072 + 3 * dbase);
        pack4_hlh(dst, v);
      }
    }
  }
}

// ---------------------------------------------------------------------------
// KV MFMA GEMM, same deep-pipeline template at 128x128 tile:
//   4 bufs x 16 KiB (A 8 frags | B 8 frags) = 64 KiB -> 2 blocks/CU.
//   96 K-tiles of 32 u16, ONE barrier per tile, vmcnt(8) counted,
//   MFMA split 8 (af[0..1]) / 8 (af[2..3]). Same ledger proof as above.
// kv[b][e][t(80pad)] = sum Wkv[e][c] Tx[b][c][t] + bkv[e]
// ---------------------------------------------------------------------------
__global__ __launch_bounds__(256) void gemm_kv_mfma(
    const u16* __restrict__ Apk, const u16* __restrict__ Bpk,
    const float* __restrict__ bias, float* __restrict__ Y)
{
  const int b  = blockIdx.y;
  const int d0 = blockIdx.x * 128;
  const int tid  = threadIdx.x;
  const int lane = tid & 63;
  const int w    = tid >> 6;       // 0..3
  const int wm   = w >> 1, wn = w & 1;
  const int lr   = lane & 15;
  const int lkb  = (lane >> 4) * 16;

  __shared__ __align__(16) char smem[65536];   // 4 bufs x (A 8K | B 8K)

  const u16* Bb = Bpk + (size_t)b * 128 * 3072;

  // wave w stages frags g = 4w..4w+3; g<8: A frag g; g>=8: B frag g-8.
  const char* gsrc[4];
  int ldst[4];
#pragma unroll
  for (int f = 0; f < 4; ++f) {
    int g = w * 4 + f;
    if (g < 8)
      gsrc[f] = (const char*)(Apk + (size_t)(d0 + g * 16 + lr) * 3072) + lkb;
    else
      gsrc[f] = (const char*)(Bb + (size_t)((g - 8) * 16 + lr) * 3072) + lkb;
    ldst[f] = g * 1024;
  }

  auto stage = [&](int t) {
    char* base = smem + (t & 3) * 16384;
#pragma unroll
    for (int f = 0; f < 4; ++f)
      async16(base + ldst[f], gsrc[f] + (size_t)t * 64);
  };

  f32x4 acc[4][4];
#pragma unroll
  for (int i = 0; i < 4; ++i)
#pragma unroll
    for (int j = 0; j < 4; ++j) acc[i][j] = (f32x4){0.f, 0.f, 0.f, 0.f};

  stage(0); stage(1); stage(2); stage(3);
  asm volatile("s_waitcnt vmcnt(12)" ::: "memory");   // tile 0 resident
  __builtin_amdgcn_s_barrier();

  for (int t = 0; t < 96; ++t) {
    const char* bufA = smem + (size_t)(t & 3) * 16384 + (size_t)lane * 16;
    const char* bufB = bufA + 8192;

    bf16x8 af[4], bfv[4];
#pragma unroll
    for (int j = 0; j < 4; ++j)
      bfv[j] = *(const bf16x8*)(bufB + (wn * 4 + j) * 1024);
    af[0] = *(const bf16x8*)(bufA + (wm * 4 + 0) * 1024);
    af[1] = *(const bf16x8*)(bufA + (wm * 4 + 1) * 1024);
    __builtin_amdgcn_s_setprio(1);
#pragma unroll
    for (int i = 0; i < 2; ++i)
#pragma unroll
      for (int j = 0; j < 4; ++j)
        acc[i][j] = __builtin_amdgcn_mfma_f32_16x16x32_bf16(af[i], bfv[j], acc[i][j], 0, 0, 0);
    __builtin_amdgcn_s_setprio(0);

    af[2] = *(const bf16x8*)(bufA + (wm * 4 + 2) * 1024);
    af[3] = *(const bf16x8*)(bufA + (wm * 4 + 3) * 1024);
    asm volatile("s_waitcnt lgkmcnt(0)" ::: "memory");  // drain BEFORE barrier
    __builtin_amdgcn_sched_barrier(0);
    if (t < 93)       asm volatile("s_waitcnt vmcnt(8)" ::: "memory");
    else if (t == 93) asm volatile("s_waitcnt vmcnt(4)" ::: "memory");
    else              asm volatile("s_waitcnt vmcnt(0)" ::: "memory");
    __builtin_amdgcn_s_barrier();
    asm volatile("" ::: "memory");
    if (t + 4 < 96) stage(t + 4);
    __builtin_amdgcn_s_setprio(1);
#pragma unroll
    for (int i = 2; i < 4; ++i)
#pragma unroll
      for (int j = 0; j < 4; ++j)
        acc[i][j] = __builtin_amdgcn_mfma_f32_16x16x32_bf16(af[i], bfv[j], acc[i][j], 0, 0, 0);
    __builtin_amdgcn_s_setprio(0);
  }

#pragma unroll
  for (int i = 0; i < 4; ++i) {
    const int dbase = d0 + wm * 64 + i * 16 + (lane >> 4) * 4;
    const float4 bv = *(const float4*)(bias + dbase);
#pragma unroll
    for (int j = 0; j < 4; ++j) {
      const int n = wn * 64 + j * 16 + lr;
      if (n < 80) {
        float* yp = Y + ((size_t)b * 2048 + dbase) * 80 + n;
        yp[0]      = acc[i][j].x + bv.x;
        yp[80]     = acc[i][j].y + bv.y;
        yp[160]    = acc[i][j].z + bv.z;
        yp[240]    = acc[i][j].w + bv.w;
      }
    }
  }
}

// ---------------------------------------------------------------------------
// MFMA attention, fused output pack. QK loop unroll 2 (batch global loads
// across 2 k-steps to cut exposed L2 latency). Otherwise unchanged.
// ---------------------------------------------------------------------------
__global__ __launch_bounds__(256, 2) void attn_mfma(
    const u16* __restrict__ qpk,   // [B][1024 n][3072] {h,l,h}
    const u16* __restrict__ ktpk,  // [B*8][80 t][384]  {h,h,l}
    const u16* __restrict__ vpk,   // [B*8][128 d][256] {h,l,h}, 240..256 = 0
    u16* __restrict__ xout)        // [B][1024 n][3072] {h,l,h} packed
{
  const int b  = blockIdx.z;
  const int h  = blockIdx.y;
  const int n0 = blockIdx.x * 128;
  const int tid  = threadIdx.x;
  const int w    = tid >> 6;
  const int lane = tid & 63;
  const int lr = lane & 15;      // frag row / output col
  const int lc = lane >> 4;      // frag k-chunk / output row group
  const float scale = 0.08838834764831845f;  // 128^-0.5

  __shared__ u16 Plds[4][32 * 256];   // 64 KiB total, wave-private slices
  u16* Pw = &Plds[w][0];

  // zero P pad cols [240,256) for this wave's 32 rows (1 x 16B store/lane)
  {
    int row = lane & 31, part = lane >> 5;
    *(uint4*)&Pw[row * 256 + 240 + part * 8] = make_uint4(0, 0, 0, 0);
  }

  // ---------------- QK^T ----------------
  const u16* qb = qpk + ((size_t)b * 1024 + n0 + w * 32 + lr) * 3072 +
                  384 * h + lc * 8;
  const u16* kb = ktpk + (size_t)(b * 8 + h) * 80 * 384 + (size_t)lr * 384 + lc * 8;

  f32x4 accs[2][5];
#pragma unroll
  for (int ni = 0; ni < 2; ++ni)
#pragma unroll
    for (int tt = 0; tt < 5; ++tt) accs[ni][tt] = (f32x4){0.f, 0.f, 0.f, 0.f};

#pragma unroll 2
  for (int ks = 0; ks < 12; ++ks) {
    bf16x8 qa[2], kt[5];
    qa[0] = *(const bf16x8*)(qb + ks * 32);
    qa[1] = *(const bf16x8*)(qb + 16 * 3072 + ks * 32);
#pragma unroll
    for (int tt = 0; tt < 5; ++tt)
      kt[tt] = *(const bf16x8*)(kb + (size_t)tt * 16 * 384 + ks * 32);
#pragma unroll
    for (int ni = 0; ni < 2; ++ni)
#pragma unroll
      for (int tt = 0; tt < 5; ++tt)
        accs[ni][tt] = __builtin_amdgcn_mfma_f32_16x16x32_bf16(qa[ni], kt[tt], accs[ni][tt], 0, 0, 0);
  }

  // mask t >= 77 (t = tt*16 + lr; only tt==4, lr>=13 invalid)
  if (lr >= 13) {
    accs[0][4] = (f32x4){-3.0e38f, -3.0e38f, -3.0e38f, -3.0e38f};
    accs[1][4] = (f32x4){-3.0e38f, -3.0e38f, -3.0e38f, -3.0e38f};
  }

  // ---------------- softmax + P pack to LDS ----------------
#pragma unroll
  for (int ni = 0; ni < 2; ++ni) {
    f32x4 mx = accs[ni][0];
#pragma unroll
    for (int tt = 1; tt < 5; ++tt) {
      mx.x = fmaxf(mx.x, accs[ni][tt].x);
      mx.y = fmaxf(mx.y, accs[ni][tt].y);
      mx.z = fmaxf(mx.z, accs[ni][tt].z);
      mx.w = fmaxf(mx.w, accs[ni][tt].w);
    }
#pragma unroll
    for (int mk = 1; mk <= 8; mk <<= 1) {
      mx.x = fmaxf(mx.x, __shfl_xor(mx.x, mk));
      mx.y = fmaxf(mx.y, __shfl_xor(mx.y, mk));
      mx.z = fmaxf(mx.z, __shfl_xor(mx.z, mk));
      mx.w = fmaxf(mx.w, __shfl_xor(mx.w, mk));
    }
    f32x4 sm = (f32x4){0.f, 0.f, 0.f, 0.f};
#pragma unroll
    for (int tt = 0; tt < 5; ++tt) {
      f32x4 e;
      e.x = __expf((accs[ni][tt].x - mx.x) * scale);
      e.y = __expf((accs[ni][tt].y - mx.y) * scale);
      e.z = __expf((accs[ni][tt].z - mx.z) * scale);
      e.w = __expf((accs[ni][tt].w - mx.w) * scale);
      accs[ni][tt] = e;
      sm += e;
    }
#pragma unroll
    for (int mk = 1; mk <= 8; mk <<= 1) {
      sm.x += __shfl_xor(sm.x, mk);
      sm.y += __shfl_xor(sm.y, mk);
      sm.z += __shfl_xor(sm.z, mk);
      sm.w += __shfl_xor(sm.w, mk);
    }
    f32x4 inv = (f32x4){1.f / sm.x, 1.f / sm.y, 1.f / sm.z, 1.f / sm.w};
    // write P {h,h,l} at [row][3t..3t+2]; row = ni*16 + lc*4 + comp, t = tt*16+lr
#pragma unroll
    for (int tt = 0; tt < 5; ++tt) {
#pragma unroll
      for (int c = 0; c < 4; ++c) {
        float pv = accs[ni][tt][c] * inv[c];
        int row = ni * 16 + lc * 4 + c;
        int t = tt * 16 + lr;
        u16 hh = f2bf(pv);
        float hf = __uint_as_float((uint32_t)hh << 16);
        u16 ll = f2bf(pv - hf);
        u16* pp = &Pw[row * 256 + 3 * t];
        pp[0] = hh; pp[1] = hh; pp[2] = ll;
      }
    }
  }

  // ---------------- PV ----------------
  f32x4 acco[2][8];
#pragma unroll
  for (int ni = 0; ni < 2; ++ni)
#pragma unroll
    for (int dj = 0; dj < 8; ++dj) acco[ni][dj] = (f32x4){0.f, 0.f, 0.f, 0.f};

  const u16* vb = vpk + (size_t)(b * 8 + h) * 128 * 256 + (size_t)lr * 256 + lc * 8;
  const u16* pb = &Pw[lr * 256 + lc * 8];

  for (int ks = 0; ks < 8; ++ks) {
    bf16x8 pa[2], vv[8];
    pa[0] = *(const bf16x8*)(pb + ks * 32);
    pa[1] = *(const bf16x8*)(pb + 16 * 256 + ks * 32);
#pragma unroll
    for (int dj = 0; dj < 8; ++dj)
      vv[dj] = *(const bf16x8*)(vb + (size_t)dj * 16 * 256 + ks * 32);
#pragma unroll
    for (int ni = 0; ni < 2; ++ni)
#pragma unroll
      for (int dj = 0; dj < 8; ++dj)
        acco[ni][dj] = __builtin_amdgcn_mfma_f32_16x16x32_bf16(pa[ni], vv[dj], acco[ni][dj], 0, 0, 0);
  }

  // ---------------- fused epilogue: pack to Xpk[b][n][3c] ----------------
  float* Pf = (float*)Pw;
#pragma unroll
  for (int ni = 0; ni < 2; ++ni)
#pragma unroll
    for (int dj = 0; dj < 8; ++dj) {
      const int dl = dj * 16 + lr;
#pragma unroll
      for (int c = 0; c < 4; ++c)
        Pf[(ni * 16 + lc * 4 + c) * 128 + dl] = acco[ni][dj][c];
    }

  const int prow = lane >> 5;   // 0..1
  const int pgrp = lane & 31;   // 0..31 (d-group of 4)
#pragma unroll
  for (int r2 = 0; r2 < 16; ++r2) {
    const int row = r2 * 2 + prow;
    f32x4 vv4 = *(const f32x4*)&Pf[row * 128 + pgrp * 4];
    float v[4] = {vv4.x, vv4.y, vv4.z, vv4.w};
    uint32_t* dst = (uint32_t*)(xout +
        ((size_t)b * 1024 + n0 + w * 32 + row) * 3072 + 384 * h + 12 * pgrp);
    pack4_hlh(dst, v);
  }
}

// ---------------------------------------------------------------------------
extern "C" void kernel_launch(void* const* d_in, const int* in_sizes, int n_in,
                              void* d_out, int out_size, void* d_ws, size_t ws_size,
                              hipStream_t stream) {
  const float* Vx  = (const float*)d_in[0];
  const float* Tx  = (const float*)d_in[1];
  const float* Wq  = (const float*)d_in[2];
  const float* bq  = (const float*)d_in[3];
  const float* Wkv = (const float*)d_in[4];
  const float* bkv = (const float*)d_in[5];
  const float* Wp  = (const float*)d_in[6];
  const float* bp  = (const float*)d_in[7];
  float* out = (float*)d_out;

  char* ws = (char*)d_ws;
  const size_t MiB = (size_t)1 << 20;
  // Lifetime-aliased layout (total 239 MiB). Step order:
  //  1 packs (W/Vx/Tx)   2 gemm#1 -> qpk (fused pack)   3 gemm kv
  //  4 pack_kt/pack_v    5 attn -> Xpk (fused pack)     6 gemm#2 -> out
  u16*   Xpk      = (u16*)(ws + 0);
  u16*   qpk      = (u16*)(ws + 96 * MiB);
  u16*   WqPk     = (u16*)(ws + 192 * MiB);
  u16*   KTpk     = (u16*)(ws + 192 * MiB);
  u16*   WkvPk    = (u16*)(ws + 198 * MiB);
  u16*   Vpk      = (u16*)(ws + 200 * MiB);
  u16*   TxPk     = (u16*)(ws + 210 * MiB);
  float* kvbuf    = (float*)(ws + 222 * MiB);
  u16*   WpPk     = (u16*)(ws + 233 * MiB);

  pack_w<<<4096, 256, 0, stream>>>(Wq, WqPk);
  pack_w<<<4096, 256, 0, stream>>>(Wp, WpPk);
  pack_w<<<8192, 256, 0, stream>>>(Wkv, WkvPk);
  pack_x<<<dim3(32, 32, 16), 256, 0, stream>>>(Vx, Xpk);
  pack_tx<<<dim3(4, 32, 16), 256, 0, stream>>>(Tx, TxPk);
  gemm_mfma<1><<<dim3(4, 4, 16), 512, 0, stream>>>(WqPk, Xpk, bq, qpk);
  gemm_kv_mfma<<<dim3(16, 16), 256, 0, stream>>>(WkvPk, TxPk, bkv, kvbuf);
  pack_kt<<<dim3(8, 16), 256, 0, stream>>>(kvbuf, KTpk);
  pack_v<<<dim3(8, 16), 256, 0, stream>>>(kvbuf, Vpk);
  attn_mfma<<<dim3(8, 8, 16), 256, 0, stream>>>(qpk, KTpk, Vpk, Xpk);
  gemm_mfma<0><<<dim3(4, 4, 16), 512, 0, stream>>>(WpPk, Xpk, bp, out);
}